// Round 1
// 2267.482 us; speedup vs baseline: 1.0283x; 1.0283x over previous
//
#include <hip/hip_runtime.h>
#include <math.h>

// ---- problem constants ----
#define VOCAB  32000
#define DMODEL 768
#define NHEAD  12
#define NLAYER 4
#define BATCH  2
#define SEQ    2048
#define HEADD  64
#define FFDIM  3072
#define MROWS  (BATCH*SEQ)   // 4096

typedef __attribute__((ext_vector_type(8))) short bf16x8;
typedef __attribute__((ext_vector_type(4))) float f32x4;

__device__ __forceinline__ unsigned short f2bf(float f) {
    union { float f; unsigned u; } v; v.f = f;
    unsigned r = v.u + 0x7fffu + ((v.u >> 16) & 1u);
    return (unsigned short)(r >> 16);
}

// async global->LDS, 16B per lane; LDS dest must be wave-uniform base (HW adds lane*16)
__device__ __forceinline__ void async_lds16(const unsigned short* g, unsigned short* l) {
    __builtin_amdgcn_global_load_lds(
        (const __attribute__((address_space(1))) unsigned int*)(const void*)g,
        (__attribute__((address_space(3))) unsigned int*)(void*)l, 16, 0, 0);
}

// ---- fp32 -> bf16 elementwise (tok_emb; [V][D] is already [N][K] for the head) ----
__global__ void cvt_bf16_x4(const float* __restrict__ in, unsigned short* __restrict__ out, int n4) {
    int i = blockIdx.x * blockDim.x + threadIdx.x;
    if (i >= n4) return;
    float4 v = ((const float4*)in)[i];
    uint2 o;
    o.x = (unsigned)f2bf(v.x) | ((unsigned)f2bf(v.y) << 16);
    o.y = (unsigned)f2bf(v.z) | ((unsigned)f2bf(v.w) << 16);
    ((uint2*)out)[i] = o;
}

// ---- W [L][K][N] fp32  ->  Wt [L][N][K] bf16 (transpose via LDS tile) ----
__global__ void transpose_cvt(const float* __restrict__ W, unsigned short* __restrict__ Wt,
                              int Kdim, int Ndim) {
    __shared__ float tile[32][33];
    int l  = blockIdx.z;
    int k0 = blockIdx.x * 32;
    int n0 = blockIdx.y * 32;
    const float* Wl = W + (size_t)l * Kdim * Ndim;
    unsigned short* Wtl = Wt + (size_t)l * Kdim * Ndim;
    int c = threadIdx.x & 31, r = threadIdx.x >> 5;  // r: 0..7
#pragma unroll
    for (int i = 0; i < 4; i++)
        tile[r + i * 8][c] = Wl[(size_t)(k0 + r + i * 8) * Ndim + n0 + c];
    __syncthreads();
#pragma unroll
    for (int i = 0; i < 4; i++)
        Wtl[(size_t)(n0 + r + i * 8) * Kdim + k0 + c] = f2bf(tile[c][r + i * 8]);
}

// ---- embedding: x[row][d] = tok[idx[row]][d] + pos[row%SEQ][d]  (block=192, one row) ----
__global__ void embed_kernel(const int* __restrict__ idx, const float* __restrict__ tok,
                             const float* __restrict__ pos, float* __restrict__ x) {
    int row = blockIdx.x;
    int t = row & (SEQ - 1);
    int tr = idx[row];
    const float4* ts = (const float4*)(tok + (size_t)tr * DMODEL);
    const float4* ps = (const float4*)(pos + (size_t)t * DMODEL);
    float4* xs = (float4*)(x + (size_t)row * DMODEL);
    int i = threadIdx.x;  // 0..191
    float4 a = ts[i], b = ps[i];
    xs[i] = make_float4(a.x + b.x, a.y + b.y, a.z + b.z, a.w + b.w);
}

// ---- layernorm: x fp32 [rows][768] -> out bf16, block=256 per row ----
__global__ void layernorm_kernel(const float* __restrict__ x, const float* __restrict__ w,
                                 const float* __restrict__ b, unsigned short* __restrict__ out) {
    int row = blockIdx.x;
    const float* xr = x + (size_t)row * DMODEL;
    int t = threadIdx.x;
    float v0 = xr[t], v1 = xr[t + 256], v2 = xr[t + 512];
    float s = v0 + v1 + v2;
    float ss = v0 * v0 + v1 * v1 + v2 * v2;
#pragma unroll
    for (int off = 32; off >= 1; off >>= 1) {
        s  += __shfl_xor(s, off);
        ss += __shfl_xor(ss, off);
    }
    __shared__ float red[8];
    int wave = t >> 6, lane = t & 63;
    if (lane == 0) { red[wave] = s; red[wave + 4] = ss; }
    __syncthreads();
    s  = red[0] + red[1] + red[2] + red[3];
    ss = red[4] + red[5] + red[6] + red[7];
    float mu = s * (1.0f / DMODEL);
    float var = ss * (1.0f / DMODEL) - mu * mu;
    float rs = rsqrtf(var + 1e-5f);
    unsigned short* orow = out + (size_t)row * DMODEL;
    orow[t]       = f2bf((v0 - mu) * rs * w[t]       + b[t]);
    orow[t + 256] = f2bf((v1 - mu) * rs * w[t + 256] + b[t + 256]);
    orow[t + 512] = f2bf((v2 - mu) * rs * w[t + 512] + b[t + 512]);
}

// ---- GEMM: C[M,N] = epi(A[M,K] @ B'[N,K]^T + bias); 128x128 tile, 4 waves, mfma 16x16x32 bf16
//      m97 structure: global_load_lds width=16 staging into linear [128][32] LDS ----
template <bool GELU_, bool RESID_, bool OUTBF16_, bool BIAS_>
__global__ __launch_bounds__(256) void gemm_kernel(
    const unsigned short* __restrict__ A,   // [M][K] bf16
    const unsigned short* __restrict__ Bw,  // [N][K] bf16
    const float* __restrict__ bias,         // [N]
    const float* resid,                     // [M][N] (may alias Cf)
    float* Cf, unsigned short* Cb,
    int Ndim, int Kdim) {
    const int bm = blockIdx.x * 128;
    const int bn = blockIdx.y * 128;
    __shared__ unsigned short As[128][32];   // linear: global_load_lds needs contiguous dest
    __shared__ unsigned short Bs[128][32];
    int tid = threadIdx.x;
    int wave = tid >> 6, lane = tid & 63;
    int wm = (wave >> 1) * 64, wn = (wave & 1) * 64;
    int quad = lane >> 4, ln = lane & 15;
    // staging geometry: chunk = 16 rows x 64B; lane l -> row l>>2, 16B slot l&3
    int srow = lane >> 2;            // 0..15
    int scol = (lane & 3) * 8;       // bf16 col within row
    f32x4 acc[4][4] = {};

    for (int k0 = 0; k0 < Kdim; k0 += 32) {
        __syncthreads();
#pragma unroll
        for (int i = 0; i < 2; i++) {
            int ch = (wave << 1) | i;   // 0..7 : rows [ch*16, ch*16+16)
            async_lds16(A  + (size_t)(bm + ch * 16 + srow) * Kdim + k0 + scol, &As[ch * 16][0]);
            async_lds16(Bw + (size_t)(bn + ch * 16 + srow) * Kdim + k0 + scol, &Bs[ch * 16][0]);
        }
        __syncthreads();   // compiler emits s_waitcnt vmcnt(0) before barrier -> LDS ready
        bf16x8 af[4], bfr[4];
#pragma unroll
        for (int tm = 0; tm < 4; tm++) af[tm]  = *(const bf16x8*)(&As[wm + tm * 16 + ln][quad * 8]);
#pragma unroll
        for (int tn = 0; tn < 4; tn++) bfr[tn] = *(const bf16x8*)(&Bs[wn + tn * 16 + ln][quad * 8]);
#pragma unroll
        for (int tm = 0; tm < 4; tm++)
#pragma unroll
            for (int tn = 0; tn < 4; tn++)
                acc[tm][tn] = __builtin_amdgcn_mfma_f32_16x16x32_bf16(af[tm], bfr[tn], acc[tm][tn], 0, 0, 0);
    }

#pragma unroll
    for (int tm = 0; tm < 4; tm++)
#pragma unroll
        for (int tn = 0; tn < 4; tn++)
#pragma unroll
            for (int r = 0; r < 4; r++) {
                int row = bm + wm + tm * 16 + quad * 4 + r;
                int col = bn + wn + tn * 16 + ln;
                float c = acc[tm][tn][r];
                if (BIAS_) c += bias[col];
                if (GELU_) c = 0.5f * c * (1.0f + erff(c * 0.70710678118654752f));
                if (RESID_) c += resid[(size_t)row * Ndim + col];
                if (OUTBF16_) Cb[(size_t)row * Ndim + col] = f2bf(c);
                else          Cf[(size_t)row * Ndim + col] = c;
            }
}

// ---- MFMA flash attention: one block = (b,h) x 128-query tile; causal; HD=64
//      qkv is now bf16 (converted in QKV-GEMM epilogue) -> no in-kernel f32->bf16 pack ----
__global__ __launch_bounds__(256) void attn_kernel(const unsigned short* __restrict__ qkv,  // [4096][2304] bf16
                                                   unsigned short* __restrict__ out) {      // [4096][768] bf16
    int qtile = blockIdx.x;            // 0..15
    int bh = blockIdx.y;               // 0..23
    int b = bh / NHEAD, h = bh % NHEAD;
    int q0 = qtile * 128;
    const unsigned short* base = qkv + (size_t)b * SEQ * (3 * DMODEL);

    __shared__ unsigned short Qs[128][72];
    __shared__ unsigned short Ks[64][72];
    __shared__ unsigned short Vs[64][72];   // transposed: Vs[d][key]
    __shared__ unsigned short Ps[128][72];

    int tid = threadIdx.x, wave = tid >> 6, lane = tid & 63;
    int quad = lane >> 4, ln = lane & 15;

    // stage Q (already bf16)
    for (int c = tid; c < 1024; c += 256) {
        int r = c >> 3, col = (c & 7) * 8;
        *(bf16x8*)(&Qs[r][col]) =
            *(const bf16x8*)(base + (size_t)(q0 + r) * (3 * DMODEL) + h * HEADD + col);
    }
    __syncthreads();

    bf16x8 qf[2][2];
#pragma unroll
    for (int tm = 0; tm < 2; tm++)
#pragma unroll
        for (int ks = 0; ks < 2; ks++)
            qf[tm][ks] = *(const bf16x8*)(&Qs[wave * 32 + tm * 16 + ln][ks * 32 + quad * 8]);

    f32x4 o[2][4] = {};
    float mst[8], lst[8];
#pragma unroll
    for (int i = 0; i < 8; i++) { mst[i] = -3.0e38f; lst[i] = 0.0f; }

    const float scale = 0.125f;  // 1/sqrt(64)
    int nkt = qtile * 2 + 2;

    for (int kt = 0; kt < nkt; kt++) {
        __syncthreads();
        // stage K [key][d] and V transposed [d][key]
        for (int c = tid; c < 512; c += 256) {
            int r = c >> 3, col = (c & 7) * 8;
            *(bf16x8*)(&Ks[r][col]) =
                *(const bf16x8*)(base + (size_t)(kt * 64 + r) * (3 * DMODEL) + DMODEL + h * HEADD + col);
            union { bf16x8 v; unsigned short u[8]; } vv;
            vv.v = *(const bf16x8*)(base + (size_t)(kt * 64 + r) * (3 * DMODEL) + 2 * DMODEL + h * HEADD + col);
#pragma unroll
            for (int j = 0; j < 8; j++) Vs[col + j][r] = vv.u[j];
        }
        __syncthreads();

        // S = Q K^T for this wave's 32 q-rows x 64 keys
        f32x4 s[2][4];
#pragma unroll
        for (int tm = 0; tm < 2; tm++)
#pragma unroll
            for (int tn = 0; tn < 4; tn++) s[tm][tn] = (f32x4){0.f, 0.f, 0.f, 0.f};
        bf16x8 kf[4][2];
#pragma unroll
        for (int tn = 0; tn < 4; tn++)
#pragma unroll
            for (int ks = 0; ks < 2; ks++)
                kf[tn][ks] = *(const bf16x8*)(&Ks[tn * 16 + ln][ks * 32 + quad * 8]);
#pragma unroll
        for (int tm = 0; tm < 2; tm++)
#pragma unroll
            for (int tn = 0; tn < 4; tn++)
#pragma unroll
                for (int ks = 0; ks < 2; ks++)
                    s[tm][tn] = __builtin_amdgcn_mfma_f32_16x16x32_bf16(qf[tm][ks], kf[tn][ks], s[tm][tn], 0, 0, 0);

        // scale + causal mask
#pragma unroll
        for (int tm = 0; tm < 2; tm++)
#pragma unroll
            for (int tn = 0; tn < 4; tn++)
#pragma unroll
                for (int r = 0; r < 4; r++) {
                    int qi = q0 + wave * 32 + tm * 16 + quad * 4 + r;
                    int kj = kt * 64 + tn * 16 + ln;
                    float sv = s[tm][tn][r] * scale;
                    s[tm][tn][r] = (kj > qi) ? -3.0e38f : sv;
                }

        // online softmax per row (tm,r); rows replicated across the 16 lanes of a quad-group
#pragma unroll
        for (int tm = 0; tm < 2; tm++)
#pragma unroll
            for (int r = 0; r < 4; r++) {
                float mx = fmaxf(fmaxf(s[tm][0][r], s[tm][1][r]), fmaxf(s[tm][2][r], s[tm][3][r]));
#pragma unroll
                for (int msk = 1; msk <= 8; msk <<= 1) mx = fmaxf(mx, __shfl_xor(mx, msk));
                int ri = tm * 4 + r;
                float mnew = fmaxf(mst[ri], mx);
                float alpha = __expf(mst[ri] - mnew);
                mst[ri] = mnew;
                float psum = 0.f;
#pragma unroll
                for (int tn = 0; tn < 4; tn++) {
                    float p = __expf(s[tm][tn][r] - mnew);
                    s[tm][tn][r] = p;
                    psum += p;
                }
#pragma unroll
                for (int msk = 1; msk <= 8; msk <<= 1) psum += __shfl_xor(psum, msk);
                lst[ri] = lst[ri] * alpha + psum;
#pragma unroll
                for (int nd = 0; nd < 4; nd++) o[tm][nd][r] *= alpha;
            }

        // P (C-layout) -> LDS (A-layout source); wave-private rows
#pragma unroll
        for (int tm = 0; tm < 2; tm++)
#pragma unroll
            for (int tn = 0; tn < 4; tn++)
#pragma unroll
                for (int r = 0; r < 4; r++)
                    Ps[wave * 32 + tm * 16 + quad * 4 + r][tn * 16 + ln] = f2bf(s[tm][tn][r]);

        // O += P V
        bf16x8 pf[2][2], vf[4][2];
#pragma unroll
        for (int tm = 0; tm < 2; tm++)
#pragma unroll
            for (int ks = 0; ks < 2; ks++)
                pf[tm][ks] = *(const bf16x8*)(&Ps[wave * 32 + tm * 16 + ln][ks * 32 + quad * 8]);
#pragma unroll
        for (int nd = 0; nd < 4; nd++)
#pragma unroll
            for (int ks = 0; ks < 2; ks++)
                vf[nd][ks] = *(const bf16x8*)(&Vs[nd * 16 + ln][ks * 32 + quad * 8]);
#pragma unroll
        for (int tm = 0; tm < 2; tm++)
#pragma unroll
            for (int nd = 0; nd < 4; nd++)
#pragma unroll
                for (int ks = 0; ks < 2; ks++)
                    o[tm][nd] = __builtin_amdgcn_mfma_f32_16x16x32_bf16(pf[tm][ks], vf[nd][ks], o[tm][nd], 0, 0, 0);
    }

    // normalize + store bf16 to [b*SEQ + t][h*64 + d]
#pragma unroll
    for (int tm = 0; tm < 2; tm++)
#pragma unroll
        for (int r = 0; r < 4; r++) {
            float inv = 1.0f / lst[tm * 4 + r];
            int trow = q0 + wave * 32 + tm * 16 + quad * 4 + r;
#pragma unroll
            for (int nd = 0; nd < 4; nd++) {
                int col = h * HEADD + nd * 16 + ln;
                out[(size_t)(b * SEQ + trow) * DMODEL + col] = f2bf(o[tm][nd][r] * inv);
            }
        }
}

extern "C" void kernel_launch(void* const* d_in, const int* in_sizes, int n_in,
                              void* d_out, int out_size, void* d_ws, size_t ws_size,
                              hipStream_t stream) {
    const int*   idx   = (const int*)  d_in[0];
    const float* tok   = (const float*)d_in[1];
    const float* pos   = (const float*)d_in[2];
    const float* ln1w  = (const float*)d_in[3];
    const float* ln1b  = (const float*)d_in[4];
    const float* Wqkv  = (const float*)d_in[5];
    const float* bqkv  = (const float*)d_in[6];
    const float* Wproj = (const float*)d_in[7];
    const float* bproj = (const float*)d_in[8];
    const float* ln2w  = (const float*)d_in[9];
    const float* ln2b  = (const float*)d_in[10];
    const float* Wfc   = (const float*)d_in[11];
    const float* bfc   = (const float*)d_in[12];
    const float* Wfc2  = (const float*)d_in[13];
    const float* bfc2  = (const float*)d_in[14];
    const float* lnfw  = (const float*)d_in[15];
    const float* lnfb  = (const float*)d_in[16];

    // scratch that dies before the head GEMM lives inside d_out (524 MB);
    // tokT + lnout survive into the head GEMM -> d_ws.
    char* ob = (char*)d_out;
    unsigned short* qkvb   = (unsigned short*)(ob + 0);          // 18,874,368 B (bf16 now)
    float*          x      = (float*)(ob + 18874368);            // 12,582,912 B
    unsigned short* ffact  = (unsigned short*)(ob + 31457280);   // 25,165,824 B
    unsigned short* attnb  = (unsigned short*)(ob + 56623104);   //  6,291,456 B
    unsigned short* WqkvT  = (unsigned short*)(ob + 62914560);   // 14,155,776 B
    unsigned short* WprojT = (unsigned short*)(ob + 77070336);   //  4,718,592 B
    unsigned short* WfcT   = (unsigned short*)(ob + 81788928);   // 18,874,368 B
    unsigned short* Wfc2T  = (unsigned short*)(ob + 100663296);  // 18,874,368 B (ends 119,537,664)
    unsigned short* tokT   = (unsigned short*)d_ws;                      // 49,152,000 B
    unsigned short* lnout  = (unsigned short*)((char*)d_ws + 49152000);  //  6,291,456 B

    // weight conversions
    cvt_bf16_x4<<<24000, 256, 0, stream>>>(tok, tokT, VOCAB * DMODEL / 4);
    transpose_cvt<<<dim3(24, 72, NLAYER), 256, 0, stream>>>(Wqkv,  WqkvT,  DMODEL, 3 * DMODEL);
    transpose_cvt<<<dim3(24, 24, NLAYER), 256, 0, stream>>>(Wproj, WprojT, DMODEL, DMODEL);
    transpose_cvt<<<dim3(24, 96, NLAYER), 256, 0, stream>>>(Wfc,   WfcT,   DMODEL, FFDIM);
    transpose_cvt<<<dim3(96, 24, NLAYER), 256, 0, stream>>>(Wfc2,  Wfc2T,  FFDIM,  DMODEL);

    embed_kernel<<<MROWS, 192, 0, stream>>>(idx, tok, pos, x);

    for (int l = 0; l < NLAYER; l++) {
        layernorm_kernel<<<MROWS, 256, 0, stream>>>(x, ln1w + l * DMODEL, ln1b + l * DMODEL, lnout);
        // QKV GEMM now emits bf16 directly (same rounding point attn used before)
        gemm_kernel<false, false, true, true><<<dim3(32, 18), 256, 0, stream>>>(
            lnout, WqkvT + (size_t)l * 3 * DMODEL * DMODEL, bqkv + l * 3 * DMODEL,
            nullptr, nullptr, qkvb, 3 * DMODEL, DMODEL);
        attn_kernel<<<dim3(16, BATCH * NHEAD), 256, 0, stream>>>(qkvb, attnb);
        gemm_kernel<false, true, false, true><<<dim3(32, 6), 256, 0, stream>>>(
            attnb, WprojT + (size_t)l * DMODEL * DMODEL, bproj + l * DMODEL,
            x, x, nullptr, DMODEL, DMODEL);
        layernorm_kernel<<<MROWS, 256, 0, stream>>>(x, ln2w + l * DMODEL, ln2b + l * DMODEL, lnout);
        gemm_kernel<true, false, true, true><<<dim3(32, 24), 256, 0, stream>>>(
            lnout, WfcT + (size_t)l * FFDIM * DMODEL, bfc + l * FFDIM,
            nullptr, nullptr, ffact, FFDIM, DMODEL);
        gemm_kernel<false, true, false, true><<<dim3(32, 6), 256, 0, stream>>>(
            ffact, Wfc2T + (size_t)l * FFDIM * DMODEL, bfc2 + l * DMODEL,
            x, x, nullptr, DMODEL, FFDIM);
    }

    layernorm_kernel<<<MROWS, 256, 0, stream>>>(x, lnfw, lnfb, lnout);
    // tied head: [4096,768] @ [32000,768]^T -> d_out fp32 (overwrites all scratch in d_out)
    gemm_kernel<false, false, false, false><<<dim3(32, 250), 256, 0, stream>>>(
        lnout, tokT, nullptr, nullptr, (float*)d_out, nullptr, VOCAB, DMODEL);
}

// Round 2
// 2244.298 us; speedup vs baseline: 1.0389x; 1.0103x over previous
//
#include <hip/hip_runtime.h>
#include <math.h>

// ---- problem constants ----
#define VOCAB  32000
#define DMODEL 768
#define NHEAD  12
#define NLAYER 4
#define BATCH  2
#define SEQ    2048
#define HEADD  64
#define FFDIM  3072
#define MROWS  (BATCH*SEQ)   // 4096

typedef __attribute__((ext_vector_type(8))) short bf16x8;
typedef __attribute__((ext_vector_type(4))) float f32x4;

__device__ __forceinline__ unsigned short f2bf(float f) {
    union { float f; unsigned u; } v; v.f = f;
    unsigned r = v.u + 0x7fffu + ((v.u >> 16) & 1u);
    return (unsigned short)(r >> 16);
}

// async global->LDS, 16B per lane; LDS dest must be wave-uniform base (HW adds lane*16)
__device__ __forceinline__ void async_lds16(const unsigned short* g, unsigned short* l) {
    __builtin_amdgcn_global_load_lds(
        (const __attribute__((address_space(1))) unsigned int*)(const void*)g,
        (__attribute__((address_space(3))) unsigned int*)(void*)l, 16, 0, 0);
}

// ---- fp32 -> bf16 elementwise (tok_emb; [V][D] is already [N][K] for the head) ----
__global__ void cvt_bf16_x4(const float* __restrict__ in, unsigned short* __restrict__ out, int n4) {
    int i = blockIdx.x * blockDim.x + threadIdx.x;
    if (i >= n4) return;
    float4 v = ((const float4*)in)[i];
    uint2 o;
    o.x = (unsigned)f2bf(v.x) | ((unsigned)f2bf(v.y) << 16);
    o.y = (unsigned)f2bf(v.z) | ((unsigned)f2bf(v.w) << 16);
    ((uint2*)out)[i] = o;
}

// ---- W [L][K][N] fp32  ->  Wt [L][N][K] bf16 (transpose via LDS tile) ----
__global__ void transpose_cvt(const float* __restrict__ W, unsigned short* __restrict__ Wt,
                              int Kdim, int Ndim) {
    __shared__ float tile[32][33];
    int l  = blockIdx.z;
    int k0 = blockIdx.x * 32;
    int n0 = blockIdx.y * 32;
    const float* Wl = W + (size_t)l * Kdim * Ndim;
    unsigned short* Wtl = Wt + (size_t)l * Kdim * Ndim;
    int c = threadIdx.x & 31, r = threadIdx.x >> 5;  // r: 0..7
#pragma unroll
    for (int i = 0; i < 4; i++)
        tile[r + i * 8][c] = Wl[(size_t)(k0 + r + i * 8) * Ndim + n0 + c];
    __syncthreads();
#pragma unroll
    for (int i = 0; i < 4; i++)
        Wtl[(size_t)(n0 + r + i * 8) * Kdim + k0 + c] = f2bf(tile[c][r + i * 8]);
}

// ---- embedding: x[row][d] = tok[idx[row]][d] + pos[row%SEQ][d]  (block=192, one row) ----
__global__ void embed_kernel(const int* __restrict__ idx, const float* __restrict__ tok,
                             const float* __restrict__ pos, float* __restrict__ x) {
    int row = blockIdx.x;
    int t = row & (SEQ - 1);
    int tr = idx[row];
    const float4* ts = (const float4*)(tok + (size_t)tr * DMODEL);
    const float4* ps = (const float4*)(pos + (size_t)t * DMODEL);
    float4* xs = (float4*)(x + (size_t)row * DMODEL);
    int i = threadIdx.x;  // 0..191
    float4 a = ts[i], b = ps[i];
    xs[i] = make_float4(a.x + b.x, a.y + b.y, a.z + b.z, a.w + b.w);
}

// ---- layernorm: x fp32 [rows][768] -> out bf16, block=256 per row ----
__global__ void layernorm_kernel(const float* __restrict__ x, const float* __restrict__ w,
                                 const float* __restrict__ b, unsigned short* __restrict__ out) {
    int row = blockIdx.x;
    const float* xr = x + (size_t)row * DMODEL;
    int t = threadIdx.x;
    float v0 = xr[t], v1 = xr[t + 256], v2 = xr[t + 512];
    float s = v0 + v1 + v2;
    float ss = v0 * v0 + v1 * v1 + v2 * v2;
#pragma unroll
    for (int off = 32; off >= 1; off >>= 1) {
        s  += __shfl_xor(s, off);
        ss += __shfl_xor(ss, off);
    }
    __shared__ float red[8];
    int wave = t >> 6, lane = t & 63;
    if (lane == 0) { red[wave] = s; red[wave + 4] = ss; }
    __syncthreads();
    s  = red[0] + red[1] + red[2] + red[3];
    ss = red[4] + red[5] + red[6] + red[7];
    float mu = s * (1.0f / DMODEL);
    float var = ss * (1.0f / DMODEL) - mu * mu;
    float rs = rsqrtf(var + 1e-5f);
    unsigned short* orow = out + (size_t)row * DMODEL;
    orow[t]       = f2bf((v0 - mu) * rs * w[t]       + b[t]);
    orow[t + 256] = f2bf((v1 - mu) * rs * w[t + 256] + b[t + 256]);
    orow[t + 512] = f2bf((v2 - mu) * rs * w[t + 512] + b[t + 512]);
}

// ---- GEMM: C[M,N] = epi(A[M,K] @ B'[N,K]^T + bias); 128x128 tile, 4 waves, mfma 16x16x32 bf16
//      m97 structure: global_load_lds width=16 staging into linear [128][32] LDS ----
template <bool GELU_, bool RESID_, bool OUTBF16_, bool BIAS_>
__global__ __launch_bounds__(256) void gemm_kernel(
    const unsigned short* __restrict__ A,   // [M][K] bf16
    const unsigned short* __restrict__ Bw,  // [N][K] bf16
    const float* __restrict__ bias,         // [N]
    const float* resid,                     // [M][N] (may alias Cf)
    float* Cf, unsigned short* Cb,
    int Ndim, int Kdim) {
    const int bm = blockIdx.x * 128;
    const int bn = blockIdx.y * 128;
    __shared__ unsigned short As[128][32];   // linear: global_load_lds needs contiguous dest
    __shared__ unsigned short Bs[128][32];
    int tid = threadIdx.x;
    int wave = tid >> 6, lane = tid & 63;
    int wm = (wave >> 1) * 64, wn = (wave & 1) * 64;
    int quad = lane >> 4, ln = lane & 15;
    int srow = lane >> 2;            // 0..15
    int scol = (lane & 3) * 8;       // bf16 col within row
    f32x4 acc[4][4] = {};

    for (int k0 = 0; k0 < Kdim; k0 += 32) {
        __syncthreads();
#pragma unroll
        for (int i = 0; i < 2; i++) {
            int ch = (wave << 1) | i;   // 0..7 : rows [ch*16, ch*16+16)
            async_lds16(A  + (size_t)(bm + ch * 16 + srow) * Kdim + k0 + scol, &As[ch * 16][0]);
            async_lds16(Bw + (size_t)(bn + ch * 16 + srow) * Kdim + k0 + scol, &Bs[ch * 16][0]);
        }
        __syncthreads();
        bf16x8 af[4], bfr[4];
#pragma unroll
        for (int tm = 0; tm < 4; tm++) af[tm]  = *(const bf16x8*)(&As[wm + tm * 16 + ln][quad * 8]);
#pragma unroll
        for (int tn = 0; tn < 4; tn++) bfr[tn] = *(const bf16x8*)(&Bs[wn + tn * 16 + ln][quad * 8]);
#pragma unroll
        for (int tm = 0; tm < 4; tm++)
#pragma unroll
            for (int tn = 0; tn < 4; tn++)
                acc[tm][tn] = __builtin_amdgcn_mfma_f32_16x16x32_bf16(af[tm], bfr[tn], acc[tm][tn], 0, 0, 0);
    }

#pragma unroll
    for (int tm = 0; tm < 4; tm++)
#pragma unroll
        for (int tn = 0; tn < 4; tn++)
#pragma unroll
            for (int r = 0; r < 4; r++) {
                int row = bm + wm + tm * 16 + quad * 4 + r;
                int col = bn + wn + tn * 16 + ln;
                float c = acc[tm][tn][r];
                if (BIAS_) c += bias[col];
                if (GELU_) c = 0.5f * c * (1.0f + erff(c * 0.70710678118654752f));
                if (RESID_) c += resid[(size_t)row * Ndim + col];
                if (OUTBF16_) Cb[(size_t)row * Ndim + col] = f2bf(c);
                else          Cf[(size_t)row * Ndim + col] = c;
            }
}

// ============================================================================
// 256x256 8-phase GEMM (head only): C[M,N] fp32 = A[M,K] @ B[N,K]^T
// 8 waves (2M x 4N, 128x64 per wave), BK=64, 2 LDS slots of (A 32KB + B 32KB).
// Region retirement schedule: per tile t (slot s=t&1), 4 quadrant phases
//   p0 (qm0,qn0): stage Ao(t+1)->s^1 ; vmcnt(6)
//   p1 (qm0,qn1): stage Bo(t+1)->s^1 ; vmcnt(10)
//   p2 (qm1,qn0): stage Ae(t+2)->s
//   p3 (qm1,qn1): stage Be(t+2)->s   ; vmcnt(8)  (vmcnt(0) at t==NT-2)
// Regions: Ae=A rows {0-63,128-191}, Ao={64-127,192-255};
//          Be=B rows {0-31,64-95,128-159,192-223}, Bo=complement.
// LDS XOR-swizzle: byte-in-row ^= (row&7)<<4, applied on BOTH the global
// source of global_load_lds (linear dest) and the ds_read address (rule #21).
// ============================================================================
__device__ __forceinline__ void stage_Ax(const unsigned short* A, int Kdim, int bm,
                                         unsigned short (*slotA)[64], int half, int ktile,
                                         int w, int lrow, int scol) {
#pragma unroll
    for (int j = 0; j < 2; j++) {
        int row = j * 128 + half * 64 + w * 8;   // wave-uniform base row
        const unsigned short* src = A + (size_t)(bm + row + lrow) * Kdim + ktile * 64 + scol;
        async_lds16(src, &slotA[row][0]);
    }
}
__device__ __forceinline__ void stage_Bx(const unsigned short* Bw, int Kdim, int bn,
                                         unsigned short (*slotB)[64], int half, int ktile,
                                         int w, int lrow, int scol) {
#pragma unroll
    for (int j = 0; j < 2; j++) {
        int gb = j * 64 + w * 8;
        int row = (gb >> 5) * 64 + half * 32 + (gb & 31);  // wave-uniform base row
        const unsigned short* src = Bw + (size_t)(bn + row + lrow) * Kdim + ktile * 64 + scol;
        async_lds16(src, &slotB[row][0]);
    }
}

#define PHASE(QM, QN, STAGE_STMT, VM_STMT)                                            \
  { bf16x8 af[4][2], bfv[2][2];                                                        \
    const char* Ab = (const char*)&lds[s][0][0][0];                                    \
    const char* Bb = (const char*)&lds[s][1][0][0];                                    \
    _Pragma("unroll") for (int j = 0; j < 4; j++) {                                    \
      int row = wr * 128 + (QM) * 64 + j * 16 + ln;                                    \
      int rs = row * 128, sw = (row & 7) << 4;                                         \
      _Pragma("unroll") for (int ks = 0; ks < 2; ks++)                                 \
        af[j][ks] = *(const bf16x8*)(Ab + rs + ((ks * 64 + quad * 16) ^ sw));          \
    }                                                                                  \
    _Pragma("unroll") for (int jn = 0; jn < 2; jn++) {                                 \
      int row = wc * 64 + (QN) * 32 + jn * 16 + ln;                                    \
      int rs = row * 128, sw = (row & 7) << 4;                                         \
      _Pragma("unroll") for (int ks = 0; ks < 2; ks++)                                 \
        bfv[jn][ks] = *(const bf16x8*)(Bb + rs + ((ks * 64 + quad * 16) ^ sw));        \
    }                                                                                  \
    STAGE_STMT;                                                                        \
    VM_STMT;                                                                           \
    __builtin_amdgcn_s_barrier(); asm volatile("" ::: "memory");                       \
    asm volatile("s_waitcnt lgkmcnt(0)" ::: "memory");                                 \
    __builtin_amdgcn_s_setprio(1);                                                     \
    _Pragma("unroll") for (int j = 0; j < 4; j++)                                      \
    _Pragma("unroll") for (int jn = 0; jn < 2; jn++)                                   \
    _Pragma("unroll") for (int ks = 0; ks < 2; ks++)                                   \
      acc[(QM) * 4 + j][(QN) * 2 + jn] = __builtin_amdgcn_mfma_f32_16x16x32_bf16(      \
          af[j][ks], bfv[jn][ks], acc[(QM) * 4 + j][(QN) * 2 + jn], 0, 0, 0);          \
    __builtin_amdgcn_s_setprio(0);                                                     \
    __builtin_amdgcn_s_barrier(); asm volatile("" ::: "memory"); }

__global__ __launch_bounds__(512, 2) void gemm256_kernel(
    const unsigned short* __restrict__ A,   // [M][K] bf16
    const unsigned short* __restrict__ Bw,  // [N][K] bf16
    float* __restrict__ Cf, int Ndim, int Kdim) {
    const int bm = blockIdx.x * 256;
    const int bn = blockIdx.y * 256;
    __shared__ unsigned short lds[2][2][256][64];   // [slot][A/B][row][col] = 128 KiB
    int tid = threadIdx.x;
    int w = tid >> 6, lane = tid & 63;
    int wr = w >> 2, wc = w & 3;
    int quad = lane >> 4, ln = lane & 15;
    int lrow = lane >> 3;                        // 0..7
    int scol = ((lane & 7) ^ lrow) << 3;         // pre-swizzled global col (bf16)
    f32x4 acc[8][4] = {};
    const int NT = Kdim >> 6;                    // 12 K-tiles of 64

    // prologue: Ae0,Be0,Ao0,Bo0,Ae1,Be1 (6 units = 12 loads); wait oldest 4 (tile-0 even regions)
    stage_Ax(A,  Kdim, bm, lds[0][0], 0, 0, w, lrow, scol);
    stage_Bx(Bw, Kdim, bn, lds[0][1], 0, 0, w, lrow, scol);
    stage_Ax(A,  Kdim, bm, lds[0][0], 1, 0, w, lrow, scol);
    stage_Bx(Bw, Kdim, bn, lds[0][1], 1, 0, w, lrow, scol);
    stage_Ax(A,  Kdim, bm, lds[1][0], 0, 1, w, lrow, scol);
    stage_Bx(Bw, Kdim, bn, lds[1][1], 0, 1, w, lrow, scol);
    asm volatile("s_waitcnt vmcnt(8)" ::: "memory");
    __builtin_amdgcn_s_barrier(); asm volatile("" ::: "memory");

    for (int t = 0; t < NT; t++) {
        const int s = t & 1;
        unsigned short (*nA)[64] = lds[s ^ 1][0];
        unsigned short (*nB)[64] = lds[s ^ 1][1];
        unsigned short (*cA)[64] = lds[s][0];
        unsigned short (*cB)[64] = lds[s][1];
        const bool st1 = (t + 1 < NT), st2 = (t + 2 < NT);

        PHASE(0, 0,
              if (st1) stage_Ax(A, Kdim, bm, nA, 1, t + 1, w, lrow, scol),
              if (st1) asm volatile("s_waitcnt vmcnt(6)" ::: "memory"))
        PHASE(0, 1,
              if (st1) stage_Bx(Bw, Kdim, bn, nB, 1, t + 1, w, lrow, scol),
              if (st1) asm volatile("s_waitcnt vmcnt(10)" ::: "memory"))
        PHASE(1, 0,
              if (st2) stage_Ax(A, Kdim, bm, cA, 0, t + 2, w, lrow, scol), )
        PHASE(1, 1,
              if (st2) stage_Bx(Bw, Kdim, bn, cB, 0, t + 2, w, lrow, scol),
              if (st2) { asm volatile("s_waitcnt vmcnt(8)" ::: "memory"); }
              else if (t == NT - 2) { asm volatile("s_waitcnt vmcnt(0)" ::: "memory"); })
    }

    // epilogue: fp32 store
#pragma unroll
    for (int mf = 0; mf < 8; mf++)
#pragma unroll
        for (int nf = 0; nf < 4; nf++)
#pragma unroll
            for (int r = 0; r < 4; r++) {
                int row = bm + wr * 128 + mf * 16 + quad * 4 + r;
                int col = bn + wc * 64 + nf * 16 + ln;
                Cf[(size_t)row * Ndim + col] = acc[mf][nf][r];
            }
}

// ---- MFMA flash attention: one block = (b,h) x 128-query tile; causal; HD=64 ----
__global__ __launch_bounds__(256) void attn_kernel(const unsigned short* __restrict__ qkv,  // [4096][2304] bf16
                                                   unsigned short* __restrict__ out) {      // [4096][768] bf16
    int qtile = blockIdx.x;            // 0..15
    int bh = blockIdx.y;               // 0..23
    int b = bh / NHEAD, h = bh % NHEAD;
    int q0 = qtile * 128;
    const unsigned short* base = qkv + (size_t)b * SEQ * (3 * DMODEL);

    __shared__ unsigned short Qs[128][72];
    __shared__ unsigned short Ks[64][72];
    __shared__ unsigned short Vs[64][72];   // transposed: Vs[d][key]
    __shared__ unsigned short Ps[128][72];

    int tid = threadIdx.x, wave = tid >> 6, lane = tid & 63;
    int quad = lane >> 4, ln = lane & 15;

    // stage Q (already bf16)
    for (int c = tid; c < 1024; c += 256) {
        int r = c >> 3, col = (c & 7) * 8;
        *(bf16x8*)(&Qs[r][col]) =
            *(const bf16x8*)(base + (size_t)(q0 + r) * (3 * DMODEL) + h * HEADD + col);
    }
    __syncthreads();

    bf16x8 qf[2][2];
#pragma unroll
    for (int tm = 0; tm < 2; tm++)
#pragma unroll
        for (int ks = 0; ks < 2; ks++)
            qf[tm][ks] = *(const bf16x8*)(&Qs[wave * 32 + tm * 16 + ln][ks * 32 + quad * 8]);

    f32x4 o[2][4] = {};
    float mst[8], lst[8];
#pragma unroll
    for (int i = 0; i < 8; i++) { mst[i] = -3.0e38f; lst[i] = 0.0f; }

    const float scale = 0.125f;  // 1/sqrt(64)
    int nkt = qtile * 2 + 2;

    for (int kt = 0; kt < nkt; kt++) {
        __syncthreads();
        // stage K [key][d] and V transposed [d][key]
        for (int c = tid; c < 512; c += 256) {
            int r = c >> 3, col = (c & 7) * 8;
            *(bf16x8*)(&Ks[r][col]) =
                *(const bf16x8*)(base + (size_t)(kt * 64 + r) * (3 * DMODEL) + DMODEL + h * HEADD + col);
            union { bf16x8 v; unsigned short u[8]; } vv;
            vv.v = *(const bf16x8*)(base + (size_t)(kt * 64 + r) * (3 * DMODEL) + 2 * DMODEL + h * HEADD + col);
#pragma unroll
            for (int j = 0; j < 8; j++) Vs[col + j][r] = vv.u[j];
        }
        __syncthreads();

        // S = Q K^T for this wave's 32 q-rows x 64 keys
        f32x4 s[2][4];
#pragma unroll
        for (int tm = 0; tm < 2; tm++)
#pragma unroll
            for (int tn = 0; tn < 4; tn++) s[tm][tn] = (f32x4){0.f, 0.f, 0.f, 0.f};
        bf16x8 kf[4][2];
#pragma unroll
        for (int tn = 0; tn < 4; tn++)
#pragma unroll
            for (int ks = 0; ks < 2; ks++)
                kf[tn][ks] = *(const bf16x8*)(&Ks[tn * 16 + ln][ks * 32 + quad * 8]);
#pragma unroll
        for (int tm = 0; tm < 2; tm++)
#pragma unroll
            for (int tn = 0; tn < 4; tn++)
#pragma unroll
                for (int ks = 0; ks < 2; ks++)
                    s[tm][tn] = __builtin_amdgcn_mfma_f32_16x16x32_bf16(qf[tm][ks], kf[tn][ks], s[tm][tn], 0, 0, 0);

        // scale + causal mask
#pragma unroll
        for (int tm = 0; tm < 2; tm++)
#pragma unroll
            for (int tn = 0; tn < 4; tn++)
#pragma unroll
                for (int r = 0; r < 4; r++) {
                    int qi = q0 + wave * 32 + tm * 16 + quad * 4 + r;
                    int kj = kt * 64 + tn * 16 + ln;
                    float sv = s[tm][tn][r] * scale;
                    s[tm][tn][r] = (kj > qi) ? -3.0e38f : sv;
                }

        // online softmax per row (tm,r); rows replicated across the 16 lanes of a quad-group
#pragma unroll
        for (int tm = 0; tm < 2; tm++)
#pragma unroll
            for (int r = 0; r < 4; r++) {
                float mx = fmaxf(fmaxf(s[tm][0][r], s[tm][1][r]), fmaxf(s[tm][2][r], s[tm][3][r]));
#pragma unroll
                for (int msk = 1; msk <= 8; msk <<= 1) mx = fmaxf(mx, __shfl_xor(mx, msk));
                int ri = tm * 4 + r;
                float mnew = fmaxf(mst[ri], mx);
                float alpha = __expf(mst[ri] - mnew);
                mst[ri] = mnew;
                float psum = 0.f;
#pragma unroll
                for (int tn = 0; tn < 4; tn++) {
                    float p = __expf(s[tm][tn][r] - mnew);
                    s[tm][tn][r] = p;
                    psum += p;
                }
#pragma unroll
                for (int msk = 1; msk <= 8; msk <<= 1) psum += __shfl_xor(psum, msk);
                lst[ri] = lst[ri] * alpha + psum;
#pragma unroll
                for (int nd = 0; nd < 4; nd++) o[tm][nd][r] *= alpha;
            }

        // P (C-layout) -> LDS (A-layout source); wave-private rows
#pragma unroll
        for (int tm = 0; tm < 2; tm++)
#pragma unroll
            for (int tn = 0; tn < 4; tn++)
#pragma unroll
                for (int r = 0; r < 4; r++)
                    Ps[wave * 32 + tm * 16 + quad * 4 + r][tn * 16 + ln] = f2bf(s[tm][tn][r]);

        // O += P V
        bf16x8 pf[2][2], vf[4][2];
#pragma unroll
        for (int tm = 0; tm < 2; tm++)
#pragma unroll
            for (int ks = 0; ks < 2; ks++)
                pf[tm][ks] = *(const bf16x8*)(&Ps[wave * 32 + tm * 16 + ln][ks * 32 + quad * 8]);
#pragma unroll
        for (int nd = 0; nd < 4; nd++)
#pragma unroll
            for (int ks = 0; ks < 2; ks++)
                vf[nd][ks] = *(const bf16x8*)(&Vs[nd * 16 + ln][ks * 32 + quad * 8]);
#pragma unroll
        for (int tm = 0; tm < 2; tm++)
#pragma unroll
            for (int nd = 0; nd < 4; nd++)
#pragma unroll
                for (int ks = 0; ks < 2; ks++)
                    o[tm][nd] = __builtin_amdgcn_mfma_f32_16x16x32_bf16(pf[tm][ks], vf[nd][ks], o[tm][nd], 0, 0, 0);
    }

    // normalize + store bf16 to [b*SEQ + t][h*64 + d]
#pragma unroll
    for (int tm = 0; tm < 2; tm++)
#pragma unroll
        for (int r = 0; r < 4; r++) {
            float inv = 1.0f / lst[tm * 4 + r];
            int trow = q0 + wave * 32 + tm * 16 + quad * 4 + r;
#pragma unroll
            for (int nd = 0; nd < 4; nd++) {
                int col = h * HEADD + nd * 16 + ln;
                out[(size_t)(b * SEQ + trow) * DMODEL + col] = f2bf(o[tm][nd][r] * inv);
            }
        }
}

extern "C" void kernel_launch(void* const* d_in, const int* in_sizes, int n_in,
                              void* d_out, int out_size, void* d_ws, size_t ws_size,
                              hipStream_t stream) {
    const int*   idx   = (const int*)  d_in[0];
    const float* tok   = (const float*)d_in[1];
    const float* pos   = (const float*)d_in[2];
    const float* ln1w  = (const float*)d_in[3];
    const float* ln1b  = (const float*)d_in[4];
    const float* Wqkv  = (const float*)d_in[5];
    const float* bqkv  = (const float*)d_in[6];
    const float* Wproj = (const float*)d_in[7];
    const float* bproj = (const float*)d_in[8];
    const float* ln2w  = (const float*)d_in[9];
    const float* ln2b  = (const float*)d_in[10];
    const float* Wfc   = (const float*)d_in[11];
    const float* bfc   = (const float*)d_in[12];
    const float* Wfc2  = (const float*)d_in[13];
    const float* bfc2  = (const float*)d_in[14];
    const float* lnfw  = (const float*)d_in[15];
    const float* lnfb  = (const float*)d_in[16];

    // scratch that dies before the head GEMM lives inside d_out (524 MB);
    // tokT + lnout survive into the head GEMM -> d_ws.
    char* ob = (char*)d_out;
    unsigned short* qkvb   = (unsigned short*)(ob + 0);          // 18,874,368 B (bf16)
    float*          x      = (float*)(ob + 18874368);            // 12,582,912 B
    unsigned short* ffact  = (unsigned short*)(ob + 31457280);   // 25,165,824 B
    unsigned short* attnb  = (unsigned short*)(ob + 56623104);   //  6,291,456 B
    unsigned short* WqkvT  = (unsigned short*)(ob + 62914560);   // 14,155,776 B
    unsigned short* WprojT = (unsigned short*)(ob + 77070336);   //  4,718,592 B
    unsigned short* WfcT   = (unsigned short*)(ob + 81788928);   // 18,874,368 B
    unsigned short* Wfc2T  = (unsigned short*)(ob + 100663296);  // 18,874,368 B (ends 119,537,664)
    unsigned short* tokT   = (unsigned short*)d_ws;                      // 49,152,000 B
    unsigned short* lnout  = (unsigned short*)((char*)d_ws + 49152000);  //  6,291,456 B

    // weight conversions
    cvt_bf16_x4<<<24000, 256, 0, stream>>>(tok, tokT, VOCAB * DMODEL / 4);
    transpose_cvt<<<dim3(24, 72, NLAYER), 256, 0, stream>>>(Wqkv,  WqkvT,  DMODEL, 3 * DMODEL);
    transpose_cvt<<<dim3(24, 24, NLAYER), 256, 0, stream>>>(Wproj, WprojT, DMODEL, DMODEL);
    transpose_cvt<<<dim3(24, 96, NLAYER), 256, 0, stream>>>(Wfc,   WfcT,   DMODEL, FFDIM);
    transpose_cvt<<<dim3(96, 24, NLAYER), 256, 0, stream>>>(Wfc2,  Wfc2T,  FFDIM,  DMODEL);

    embed_kernel<<<MROWS, 192, 0, stream>>>(idx, tok, pos, x);

    for (int l = 0; l < NLAYER; l++) {
        layernorm_kernel<<<MROWS, 256, 0, stream>>>(x, ln1w + l * DMODEL, ln1b + l * DMODEL, lnout);
        gemm_kernel<false, false, true, true><<<dim3(32, 18), 256, 0, stream>>>(
            lnout, WqkvT + (size_t)l * 3 * DMODEL * DMODEL, bqkv + l * 3 * DMODEL,
            nullptr, nullptr, qkvb, 3 * DMODEL, DMODEL);
        attn_kernel<<<dim3(16, BATCH * NHEAD), 256, 0, stream>>>(qkvb, attnb);
        gemm_kernel<false, true, false, true><<<dim3(32, 6), 256, 0, stream>>>(
            attnb, WprojT + (size_t)l * DMODEL * DMODEL, bproj + l * DMODEL,
            x, x, nullptr, DMODEL, DMODEL);
        layernorm_kernel<<<MROWS, 256, 0, stream>>>(x, ln2w + l * DMODEL, ln2b + l * DMODEL, lnout);
        gemm_kernel<true, false, true, true><<<dim3(32, 24), 256, 0, stream>>>(
            lnout, WfcT + (size_t)l * FFDIM * DMODEL, bfc + l * FFDIM,
            nullptr, nullptr, ffact, FFDIM, DMODEL);
        gemm_kernel<false, true, false, true><<<dim3(32, 6), 256, 0, stream>>>(
            ffact, Wfc2T + (size_t)l * FFDIM * DMODEL, bfc2 + l * DMODEL,
            x, x, nullptr, DMODEL, FFDIM);
    }

    layernorm_kernel<<<MROWS, 256, 0, stream>>>(x, lnfw, lnfb, lnout);
    // tied head: [4096,768] @ [32000,768]^T -> d_out fp32 (8-phase 256^2 kernel)
    gemm256_kernel<<<dim3(16, 125), 512, 0, stream>>>(lnout, tokT, (float*)d_out, VOCAB, DMODEL);
}

// Round 3
// 2172.978 us; speedup vs baseline: 1.0730x; 1.0328x over previous
//
#include <hip/hip_runtime.h>
#include <math.h>

// ---- problem constants ----
#define VOCAB  32000
#define DMODEL 768
#define NHEAD  12
#define NLAYER 4
#define BATCH  2
#define SEQ    2048
#define HEADD  64
#define FFDIM  3072
#define MROWS  (BATCH*SEQ)   // 4096

typedef __attribute__((ext_vector_type(8))) short bf16x8;
typedef __attribute__((ext_vector_type(4))) float f32x4;

__device__ __forceinline__ unsigned short f2bf(float f) {
    union { float f; unsigned u; } v; v.f = f;
    unsigned r = v.u + 0x7fffu + ((v.u >> 16) & 1u);
    return (unsigned short)(r >> 16);
}

// async global->LDS, 16B per lane; LDS dest must be wave-uniform base (HW adds lane*16)
__device__ __forceinline__ void async_lds16(const unsigned short* g, unsigned short* l) {
    __builtin_amdgcn_global_load_lds(
        (const __attribute__((address_space(1))) unsigned int*)(const void*)g,
        (__attribute__((address_space(3))) unsigned int*)(void*)l, 16, 0, 0);
}

// ---- fp32 -> bf16 elementwise (tok_emb; [V][D] is already [N][K] for the head) ----
__global__ void cvt_bf16_x4(const float* __restrict__ in, unsigned short* __restrict__ out, int n4) {
    int i = blockIdx.x * blockDim.x + threadIdx.x;
    if (i >= n4) return;
    float4 v = ((const float4*)in)[i];
    uint2 o;
    o.x = (unsigned)f2bf(v.x) | ((unsigned)f2bf(v.y) << 16);
    o.y = (unsigned)f2bf(v.z) | ((unsigned)f2bf(v.w) << 16);
    ((uint2*)out)[i] = o;
}

// ---- W [L][K][N] fp32  ->  Wt [L][N][K] bf16 (transpose via LDS tile) ----
__global__ void transpose_cvt(const float* __restrict__ W, unsigned short* __restrict__ Wt,
                              int Kdim, int Ndim) {
    __shared__ float tile[32][33];
    int l  = blockIdx.z;
    int k0 = blockIdx.x * 32;
    int n0 = blockIdx.y * 32;
    const float* Wl = W + (size_t)l * Kdim * Ndim;
    unsigned short* Wtl = Wt + (size_t)l * Kdim * Ndim;
    int c = threadIdx.x & 31, r = threadIdx.x >> 5;  // r: 0..7
#pragma unroll
    for (int i = 0; i < 4; i++)
        tile[r + i * 8][c] = Wl[(size_t)(k0 + r + i * 8) * Ndim + n0 + c];
    __syncthreads();
#pragma unroll
    for (int i = 0; i < 4; i++)
        Wtl[(size_t)(n0 + r + i * 8) * Kdim + k0 + c] = f2bf(tile[c][r + i * 8]);
}

// ---- embedding: x[row][d] = tok[idx[row]][d] + pos[row%SEQ][d]  (block=192, one row) ----
__global__ void embed_kernel(const int* __restrict__ idx, const float* __restrict__ tok,
                             const float* __restrict__ pos, float* __restrict__ x) {
    int row = blockIdx.x;
    int t = row & (SEQ - 1);
    int tr = idx[row];
    const float4* ts = (const float4*)(tok + (size_t)tr * DMODEL);
    const float4* ps = (const float4*)(pos + (size_t)t * DMODEL);
    float4* xs = (float4*)(x + (size_t)row * DMODEL);
    int i = threadIdx.x;  // 0..191
    float4 a = ts[i], b = ps[i];
    xs[i] = make_float4(a.x + b.x, a.y + b.y, a.z + b.z, a.w + b.w);
}

// ---- layernorm: x fp32 [rows][768] -> out bf16, block=256 per row ----
__global__ void layernorm_kernel(const float* __restrict__ x, const float* __restrict__ w,
                                 const float* __restrict__ b, unsigned short* __restrict__ out) {
    int row = blockIdx.x;
    const float* xr = x + (size_t)row * DMODEL;
    int t = threadIdx.x;
    float v0 = xr[t], v1 = xr[t + 256], v2 = xr[t + 512];
    float s = v0 + v1 + v2;
    float ss = v0 * v0 + v1 * v1 + v2 * v2;
#pragma unroll
    for (int off = 32; off >= 1; off >>= 1) {
        s  += __shfl_xor(s, off);
        ss += __shfl_xor(ss, off);
    }
    __shared__ float red[8];
    int wave = t >> 6, lane = t & 63;
    if (lane == 0) { red[wave] = s; red[wave + 4] = ss; }
    __syncthreads();
    s  = red[0] + red[1] + red[2] + red[3];
    ss = red[4] + red[5] + red[6] + red[7];
    float mu = s * (1.0f / DMODEL);
    float var = ss * (1.0f / DMODEL) - mu * mu;
    float rs = rsqrtf(var + 1e-5f);
    unsigned short* orow = out + (size_t)row * DMODEL;
    orow[t]       = f2bf((v0 - mu) * rs * w[t]       + b[t]);
    orow[t + 256] = f2bf((v1 - mu) * rs * w[t + 256] + b[t + 256]);
    orow[t + 512] = f2bf((v2 - mu) * rs * w[t + 512] + b[t + 512]);
}

// ---- GEMM: C[M,N] = epi(A[M,K] @ B'[N,K]^T + bias); 128x128 tile, 4 waves, mfma 16x16x32 bf16 ----
template <bool GELU_, bool RESID_, bool OUTBF16_, bool BIAS_>
__global__ __launch_bounds__(256) void gemm_kernel(
    const unsigned short* __restrict__ A,   // [M][K] bf16
    const unsigned short* __restrict__ Bw,  // [N][K] bf16
    const float* __restrict__ bias,         // [N]
    const float* resid,                     // [M][N] (may alias Cf)
    float* Cf, unsigned short* Cb,
    int Ndim, int Kdim) {
    const int bm = blockIdx.x * 128;
    const int bn = blockIdx.y * 128;
    __shared__ unsigned short As[128][32];   // linear: global_load_lds needs contiguous dest
    __shared__ unsigned short Bs[128][32];
    int tid = threadIdx.x;
    int wave = tid >> 6, lane = tid & 63;
    int wm = (wave >> 1) * 64, wn = (wave & 1) * 64;
    int quad = lane >> 4, ln = lane & 15;
    int srow = lane >> 2;            // 0..15
    int scol = (lane & 3) * 8;       // bf16 col within row
    f32x4 acc[4][4] = {};

    for (int k0 = 0; k0 < Kdim; k0 += 32) {
        __syncthreads();
#pragma unroll
        for (int i = 0; i < 2; i++) {
            int ch = (wave << 1) | i;   // 0..7 : rows [ch*16, ch*16+16)
            async_lds16(A  + (size_t)(bm + ch * 16 + srow) * Kdim + k0 + scol, &As[ch * 16][0]);
            async_lds16(Bw + (size_t)(bn + ch * 16 + srow) * Kdim + k0 + scol, &Bs[ch * 16][0]);
        }
        __syncthreads();
        bf16x8 af[4], bfr[4];
#pragma unroll
        for (int tm = 0; tm < 4; tm++) af[tm]  = *(const bf16x8*)(&As[wm + tm * 16 + ln][quad * 8]);
#pragma unroll
        for (int tn = 0; tn < 4; tn++) bfr[tn] = *(const bf16x8*)(&Bs[wn + tn * 16 + ln][quad * 8]);
#pragma unroll
        for (int tm = 0; tm < 4; tm++)
#pragma unroll
            for (int tn = 0; tn < 4; tn++)
                acc[tm][tn] = __builtin_amdgcn_mfma_f32_16x16x32_bf16(af[tm], bfr[tn], acc[tm][tn], 0, 0, 0);
    }

#pragma unroll
    for (int tm = 0; tm < 4; tm++)
#pragma unroll
        for (int tn = 0; tn < 4; tn++)
#pragma unroll
            for (int r = 0; r < 4; r++) {
                int row = bm + wm + tm * 16 + quad * 4 + r;
                int col = bn + wn + tn * 16 + ln;
                float c = acc[tm][tn][r];
                if (BIAS_) c += bias[col];
                if (GELU_) c = 0.5f * c * (1.0f + erff(c * 0.70710678118654752f));
                if (RESID_) c += resid[(size_t)row * Ndim + col];
                if (OUTBF16_) Cb[(size_t)row * Ndim + col] = f2bf(c);
                else          Cf[(size_t)row * Ndim + col] = c;
            }
}

// ============================================================================
// 256x256 8-phase GEMM (head only) — unchanged from round 2
// ============================================================================
__device__ __forceinline__ void stage_Ax(const unsigned short* A, int Kdim, int bm,
                                         unsigned short (*slotA)[64], int half, int ktile,
                                         int w, int lrow, int scol) {
#pragma unroll
    for (int j = 0; j < 2; j++) {
        int row = j * 128 + half * 64 + w * 8;   // wave-uniform base row
        const unsigned short* src = A + (size_t)(bm + row + lrow) * Kdim + ktile * 64 + scol;
        async_lds16(src, &slotA[row][0]);
    }
}
__device__ __forceinline__ void stage_Bx(const unsigned short* Bw, int Kdim, int bn,
                                         unsigned short (*slotB)[64], int half, int ktile,
                                         int w, int lrow, int scol) {
#pragma unroll
    for (int j = 0; j < 2; j++) {
        int gb = j * 64 + w * 8;
        int row = (gb >> 5) * 64 + half * 32 + (gb & 31);  // wave-uniform base row
        const unsigned short* src = Bw + (size_t)(bn + row + lrow) * Kdim + ktile * 64 + scol;
        async_lds16(src, &slotB[row][0]);
    }
}

#define PHASE(QM, QN, STAGE_STMT, VM_STMT)                                            \
  { bf16x8 af[4][2], bfv[2][2];                                                        \
    const char* Ab = (const char*)&lds[s][0][0][0];                                    \
    const char* Bb = (const char*)&lds[s][1][0][0];                                    \
    _Pragma("unroll") for (int j = 0; j < 4; j++) {                                    \
      int row = wr * 128 + (QM) * 64 + j * 16 + ln;                                    \
      int rs = row * 128, sw = (row & 7) << 4;                                         \
      _Pragma("unroll") for (int ks = 0; ks < 2; ks++)                                 \
        af[j][ks] = *(const bf16x8*)(Ab + rs + ((ks * 64 + quad * 16) ^ sw));          \
    }                                                                                  \
    _Pragma("unroll") for (int jn = 0; jn < 2; jn++) {                                 \
      int row = wc * 64 + (QN) * 32 + jn * 16 + ln;                                    \
      int rs = row * 128, sw = (row & 7) << 4;                                         \
      _Pragma("unroll") for (int ks = 0; ks < 2; ks++)                                 \
        bfv[jn][ks] = *(const bf16x8*)(Bb + rs + ((ks * 64 + quad * 16) ^ sw));        \
    }                                                                                  \
    STAGE_STMT;                                                                        \
    VM_STMT;                                                                           \
    __builtin_amdgcn_s_barrier(); asm volatile("" ::: "memory");                       \
    asm volatile("s_waitcnt lgkmcnt(0)" ::: "memory");                                 \
    __builtin_amdgcn_s_setprio(1);                                                     \
    _Pragma("unroll") for (int j = 0; j < 4; j++)                                      \
    _Pragma("unroll") for (int jn = 0; jn < 2; jn++)                                   \
    _Pragma("unroll") for (int ks = 0; ks < 2; ks++)                                   \
      acc[(QM) * 4 + j][(QN) * 2 + jn] = __builtin_amdgcn_mfma_f32_16x16x32_bf16(      \
          af[j][ks], bfv[jn][ks], acc[(QM) * 4 + j][(QN) * 2 + jn], 0, 0, 0);          \
    __builtin_amdgcn_s_setprio(0);                                                     \
    __builtin_amdgcn_s_barrier(); asm volatile("" ::: "memory"); }

__global__ __launch_bounds__(512, 2) void gemm256_kernel(
    const unsigned short* __restrict__ A,   // [M][K] bf16
    const unsigned short* __restrict__ Bw,  // [N][K] bf16
    float* __restrict__ Cf, int Ndim, int Kdim) {
    const int bm = blockIdx.x * 256;
    const int bn = blockIdx.y * 256;
    __shared__ unsigned short lds[2][2][256][64];   // [slot][A/B][row][col] = 128 KiB
    int tid = threadIdx.x;
    int w = tid >> 6, lane = tid & 63;
    int wr = w >> 2, wc = w & 3;
    int quad = lane >> 4, ln = lane & 15;
    int lrow = lane >> 3;                        // 0..7
    int scol = ((lane & 7) ^ lrow) << 3;         // pre-swizzled global col (bf16)
    f32x4 acc[8][4] = {};
    const int NT = Kdim >> 6;                    // 12 K-tiles of 64

    stage_Ax(A,  Kdim, bm, lds[0][0], 0, 0, w, lrow, scol);
    stage_Bx(Bw, Kdim, bn, lds[0][1], 0, 0, w, lrow, scol);
    stage_Ax(A,  Kdim, bm, lds[0][0], 1, 0, w, lrow, scol);
    stage_Bx(Bw, Kdim, bn, lds[0][1], 1, 0, w, lrow, scol);
    stage_Ax(A,  Kdim, bm, lds[1][0], 0, 1, w, lrow, scol);
    stage_Bx(Bw, Kdim, bn, lds[1][1], 0, 1, w, lrow, scol);
    asm volatile("s_waitcnt vmcnt(8)" ::: "memory");
    __builtin_amdgcn_s_barrier(); asm volatile("" ::: "memory");

    for (int t = 0; t < NT; t++) {
        const int s = t & 1;
        unsigned short (*nA)[64] = lds[s ^ 1][0];
        unsigned short (*nB)[64] = lds[s ^ 1][1];
        unsigned short (*cA)[64] = lds[s][0];
        unsigned short (*cB)[64] = lds[s][1];
        const bool st1 = (t + 1 < NT), st2 = (t + 2 < NT);

        PHASE(0, 0,
              if (st1) stage_Ax(A, Kdim, bm, nA, 1, t + 1, w, lrow, scol),
              if (st1) asm volatile("s_waitcnt vmcnt(6)" ::: "memory"))
        PHASE(0, 1,
              if (st1) stage_Bx(Bw, Kdim, bn, nB, 1, t + 1, w, lrow, scol),
              if (st1) asm volatile("s_waitcnt vmcnt(10)" ::: "memory"))
        PHASE(1, 0,
              if (st2) stage_Ax(A, Kdim, bm, cA, 0, t + 2, w, lrow, scol), )
        PHASE(1, 1,
              if (st2) stage_Bx(Bw, Kdim, bn, cB, 0, t + 2, w, lrow, scol),
              if (st2) { asm volatile("s_waitcnt vmcnt(8)" ::: "memory"); }
              else if (t == NT - 2) { asm volatile("s_waitcnt vmcnt(0)" ::: "memory"); })
    }

#pragma unroll
    for (int mf = 0; mf < 8; mf++)
#pragma unroll
        for (int nf = 0; nf < 4; nf++)
#pragma unroll
            for (int r = 0; r < 4; r++) {
                int row = bm + wr * 128 + mf * 16 + quad * 4 + r;
                int col = bn + wc * 64 + nf * 16 + ln;
                Cf[(size_t)row * Ndim + col] = acc[mf][nf][r];
            }
}

// ---- MFMA flash attention: one block = (b,h) x 128-query tile; causal; HD=64
//      8 waves x 16 q-rows/wave (512 threads): 2x waves/SIMD vs 4-wave version,
//      half the per-wave serial softmax. Heavy qtiles dispatched first.
//      Mask VALU skipped on fully-unmasked KV tiles (kt < 2*qtile). ----
__global__ __launch_bounds__(512, 2) void attn_kernel(const unsigned short* __restrict__ qkv,  // [4096][2304] bf16
                                                      unsigned short* __restrict__ out) {      // [4096][768] bf16
    int qtile = 15 - blockIdx.x;       // heavy tiles first (nkt = 2*qtile+2)
    int bh = blockIdx.y;               // 0..23
    int b = bh / NHEAD, h = bh % NHEAD;
    int q0 = qtile * 128;
    const unsigned short* base = qkv + (size_t)b * SEQ * (3 * DMODEL);

    __shared__ unsigned short Qs[128][72];
    __shared__ unsigned short Ks[64][72];
    __shared__ unsigned short Vs[64][72];   // transposed: Vs[d][key]
    __shared__ unsigned short Ps[128][72];

    int tid = threadIdx.x, wave = tid >> 6, lane = tid & 63;
    int quad = lane >> 4, ln = lane & 15;

    // stage Q (bf16), 512 threads x 2 chunks
    for (int c = tid; c < 1024; c += 512) {
        int r = c >> 3, col = (c & 7) * 8;
        *(bf16x8*)(&Qs[r][col]) =
            *(const bf16x8*)(base + (size_t)(q0 + r) * (3 * DMODEL) + h * HEADD + col);
    }
    __syncthreads();

    // wave owns q-rows [wave*16, wave*16+16)
    bf16x8 qf[2];
#pragma unroll
    for (int ks = 0; ks < 2; ks++)
        qf[ks] = *(const bf16x8*)(&Qs[wave * 16 + ln][ks * 32 + quad * 8]);

    f32x4 o[4] = {};
    float mst[4], lst[4];
#pragma unroll
    for (int i = 0; i < 4; i++) { mst[i] = -3.0e38f; lst[i] = 0.0f; }

    const float scale = 0.125f;  // 1/sqrt(64)
    int nkt = qtile * 2 + 2;

    for (int kt = 0; kt < nkt; kt++) {
        __syncthreads();
        // stage K [key][d] and V transposed [d][key]; one chunk per thread
        {
            int c = tid;  // 0..511
            int r = c >> 3, col = (c & 7) * 8;
            *(bf16x8*)(&Ks[r][col]) =
                *(const bf16x8*)(base + (size_t)(kt * 64 + r) * (3 * DMODEL) + DMODEL + h * HEADD + col);
            union { bf16x8 v; unsigned short u[8]; } vv;
            vv.v = *(const bf16x8*)(base + (size_t)(kt * 64 + r) * (3 * DMODEL) + 2 * DMODEL + h * HEADD + col);
#pragma unroll
            for (int j = 0; j < 8; j++) Vs[col + j][r] = vv.u[j];
        }
        __syncthreads();

        // S = Q K^T for this wave's 16 q-rows x 64 keys
        f32x4 s[4];
#pragma unroll
        for (int tn = 0; tn < 4; tn++) s[tn] = (f32x4){0.f, 0.f, 0.f, 0.f};
        bf16x8 kf[4][2];
#pragma unroll
        for (int tn = 0; tn < 4; tn++)
#pragma unroll
            for (int ks = 0; ks < 2; ks++)
                kf[tn][ks] = *(const bf16x8*)(&Ks[tn * 16 + ln][ks * 32 + quad * 8]);
#pragma unroll
        for (int tn = 0; tn < 4; tn++)
#pragma unroll
            for (int ks = 0; ks < 2; ks++)
                s[tn] = __builtin_amdgcn_mfma_f32_16x16x32_bf16(qf[ks], kf[tn][ks], s[tn], 0, 0, 0);

        // scale (+ causal mask only on diagonal-touching tiles)
        if (kt >= qtile * 2) {
#pragma unroll
            for (int tn = 0; tn < 4; tn++)
#pragma unroll
                for (int r = 0; r < 4; r++) {
                    int qi = q0 + wave * 16 + quad * 4 + r;
                    int kj = kt * 64 + tn * 16 + ln;
                    float sv = s[tn][r] * scale;
                    s[tn][r] = (kj > qi) ? -3.0e38f : sv;
                }
        } else {
#pragma unroll
            for (int tn = 0; tn < 4; tn++)
#pragma unroll
                for (int r = 0; r < 4; r++) s[tn][r] *= scale;
        }

        // online softmax per row r (rows replicated across the 16 ln-lanes of a quad-group)
#pragma unroll
        for (int r = 0; r < 4; r++) {
            float mx = fmaxf(fmaxf(s[0][r], s[1][r]), fmaxf(s[2][r], s[3][r]));
#pragma unroll
            for (int msk = 1; msk <= 8; msk <<= 1) mx = fmaxf(mx, __shfl_xor(mx, msk));
            float mnew = fmaxf(mst[r], mx);
            float alpha = __expf(mst[r] - mnew);
            mst[r] = mnew;
            float psum = 0.f;
#pragma unroll
            for (int tn = 0; tn < 4; tn++) {
                float p = __expf(s[tn][r] - mnew);
                s[tn][r] = p;
                psum += p;
            }
#pragma unroll
            for (int msk = 1; msk <= 8; msk <<= 1) psum += __shfl_xor(psum, msk);
            lst[r] = lst[r] * alpha + psum;
#pragma unroll
            for (int nd = 0; nd < 4; nd++) o[nd][r] *= alpha;
        }

        // P (C-layout) -> LDS (A-layout source); wave-private rows
#pragma unroll
        for (int tn = 0; tn < 4; tn++)
#pragma unroll
            for (int r = 0; r < 4; r++)
                Ps[wave * 16 + quad * 4 + r][tn * 16 + ln] = f2bf(s[tn][r]);

        // O += P V
        bf16x8 pf[2], vf[4][2];
#pragma unroll
        for (int ks = 0; ks < 2; ks++)
            pf[ks] = *(const bf16x8*)(&Ps[wave * 16 + ln][ks * 32 + quad * 8]);
#pragma unroll
        for (int nd = 0; nd < 4; nd++)
#pragma unroll
            for (int ks = 0; ks < 2; ks++)
                vf[nd][ks] = *(const bf16x8*)(&Vs[nd * 16 + ln][ks * 32 + quad * 8]);
#pragma unroll
        for (int nd = 0; nd < 4; nd++)
#pragma unroll
            for (int ks = 0; ks < 2; ks++)
                o[nd] = __builtin_amdgcn_mfma_f32_16x16x32_bf16(pf[ks], vf[nd][ks], o[nd], 0, 0, 0);
    }

    // normalize + store bf16 to [b*SEQ + t][h*64 + d]
#pragma unroll
    for (int r = 0; r < 4; r++) {
        float inv = 1.0f / lst[r];
        int trow = q0 + wave * 16 + quad * 4 + r;
#pragma unroll
        for (int nd = 0; nd < 4; nd++) {
            int col = h * HEADD + nd * 16 + ln;
            out[(size_t)(b * SEQ + trow) * DMODEL + col] = f2bf(o[nd][r] * inv);
        }
    }
}

extern "C" void kernel_launch(void* const* d_in, const int* in_sizes, int n_in,
                              void* d_out, int out_size, void* d_ws, size_t ws_size,
                              hipStream_t stream) {
    const int*   idx   = (const int*)  d_in[0];
    const float* tok   = (const float*)d_in[1];
    const float* pos   = (const float*)d_in[2];
    const float* ln1w  = (const float*)d_in[3];
    const float* ln1b  = (const float*)d_in[4];
    const float* Wqkv  = (const float*)d_in[5];
    const float* bqkv  = (const float*)d_in[6];
    const float* Wproj = (const float*)d_in[7];
    const float* bproj = (const float*)d_in[8];
    const float* ln2w  = (const float*)d_in[9];
    const float* ln2b  = (const float*)d_in[10];
    const float* Wfc   = (const float*)d_in[11];
    const float* bfc   = (const float*)d_in[12];
    const float* Wfc2  = (const float*)d_in[13];
    const float* bfc2  = (const float*)d_in[14];
    const float* lnfw  = (const float*)d_in[15];
    const float* lnfb  = (const float*)d_in[16];

    // scratch that dies before the head GEMM lives inside d_out (524 MB);
    // tokT + lnout survive into the head GEMM -> d_ws.
    char* ob = (char*)d_out;
    unsigned short* qkvb   = (unsigned short*)(ob + 0);          // 18,874,368 B (bf16)
    float*          x      = (float*)(ob + 18874368);            // 12,582,912 B
    unsigned short* ffact  = (unsigned short*)(ob + 31457280);   // 25,165,824 B
    unsigned short* attnb  = (unsigned short*)(ob + 56623104);   //  6,291,456 B
    unsigned short* WqkvT  = (unsigned short*)(ob + 62914560);   // 14,155,776 B
    unsigned short* WprojT = (unsigned short*)(ob + 77070336);   //  4,718,592 B
    unsigned short* WfcT   = (unsigned short*)(ob + 81788928);   // 18,874,368 B
    unsigned short* Wfc2T  = (unsigned short*)(ob + 100663296);  // 18,874,368 B (ends 119,537,664)
    unsigned short* tokT   = (unsigned short*)d_ws;                      // 49,152,000 B
    unsigned short* lnout  = (unsigned short*)((char*)d_ws + 49152000);  //  6,291,456 B

    // weight conversions
    cvt_bf16_x4<<<24000, 256, 0, stream>>>(tok, tokT, VOCAB * DMODEL / 4);
    transpose_cvt<<<dim3(24, 72, NLAYER), 256, 0, stream>>>(Wqkv,  WqkvT,  DMODEL, 3 * DMODEL);
    transpose_cvt<<<dim3(24, 24, NLAYER), 256, 0, stream>>>(Wproj, WprojT, DMODEL, DMODEL);
    transpose_cvt<<<dim3(24, 96, NLAYER), 256, 0, stream>>>(Wfc,   WfcT,   DMODEL, FFDIM);
    transpose_cvt<<<dim3(96, 24, NLAYER), 256, 0, stream>>>(Wfc2,  Wfc2T,  FFDIM,  DMODEL);

    embed_kernel<<<MROWS, 192, 0, stream>>>(idx, tok, pos, x);

    for (int l = 0; l < NLAYER; l++) {
        layernorm_kernel<<<MROWS, 256, 0, stream>>>(x, ln1w + l * DMODEL, ln1b + l * DMODEL, lnout);
        gemm_kernel<false, false, true, true><<<dim3(32, 18), 256, 0, stream>>>(
            lnout, WqkvT + (size_t)l * 3 * DMODEL * DMODEL, bqkv + l * 3 * DMODEL,
            nullptr, nullptr, qkvb, 3 * DMODEL, DMODEL);
        attn_kernel<<<dim3(16, BATCH * NHEAD), 512, 0, stream>>>(qkvb, attnb);
        gemm_kernel<false, true, false, true><<<dim3(32, 6), 256, 0, stream>>>(
            attnb, WprojT + (size_t)l * DMODEL * DMODEL, bproj + l * DMODEL,
            x, x, nullptr, DMODEL, DMODEL);
        layernorm_kernel<<<MROWS, 256, 0, stream>>>(x, ln2w + l * DMODEL, ln2b + l * DMODEL, lnout);
        gemm_kernel<true, false, true, true><<<dim3(32, 24), 256, 0, stream>>>(
            lnout, WfcT + (size_t)l * FFDIM * DMODEL, bfc + l * FFDIM,
            nullptr, nullptr, ffact, FFDIM, DMODEL);
        gemm_kernel<false, true, false, true><<<dim3(32, 6), 256, 0, stream>>>(
            ffact, Wfc2T + (size_t)l * FFDIM * DMODEL, bfc2 + l * DMODEL,
            x, x, nullptr, DMODEL, FFDIM);
    }

    layernorm_kernel<<<MROWS, 256, 0, stream>>>(x, lnfw, lnfb, lnout);
    // tied head: [4096,768] @ [32000,768]^T -> d_out fp32 (8-phase 256^2 kernel)
    gemm256_kernel<<<dim3(16, 125), 512, 0, stream>>>(lnout, tokT, (float*)d_out, VOCAB, DMODEL);
}

// Round 4
// 2102.555 us; speedup vs baseline: 1.1090x; 1.0335x over previous
//
#include <hip/hip_runtime.h>
#include <math.h>

// ---- problem constants ----
#define VOCAB  32000
#define DMODEL 768
#define NHEAD  12
#define NLAYER 4
#define BATCH  2
#define SEQ    2048
#define HEADD  64
#define FFDIM  3072
#define MROWS  (BATCH*SEQ)   // 4096

typedef __attribute__((ext_vector_type(8))) short bf16x8;
typedef __attribute__((ext_vector_type(4))) float f32x4;

__device__ __forceinline__ unsigned short f2bf(float f) {
    union { float f; unsigned u; } v; v.f = f;
    unsigned r = v.u + 0x7fffu + ((v.u >> 16) & 1u);
    return (unsigned short)(r >> 16);
}

// async global->LDS, 16B per lane; LDS dest must be wave-uniform base (HW adds lane*16)
__device__ __forceinline__ void async_lds16(const unsigned short* g, unsigned short* l) {
    __builtin_amdgcn_global_load_lds(
        (const __attribute__((address_space(1))) unsigned int*)(const void*)g,
        (__attribute__((address_space(3))) unsigned int*)(void*)l, 16, 0, 0);
}

// ---- fp32 -> bf16 elementwise (tok_emb; [V][D] is already [N][K] for the head) ----
__global__ void cvt_bf16_x4(const float* __restrict__ in, unsigned short* __restrict__ out, int n4) {
    int i = blockIdx.x * blockDim.x + threadIdx.x;
    if (i >= n4) return;
    float4 v = ((const float4*)in)[i];
    uint2 o;
    o.x = (unsigned)f2bf(v.x) | ((unsigned)f2bf(v.y) << 16);
    o.y = (unsigned)f2bf(v.z) | ((unsigned)f2bf(v.w) << 16);
    ((uint2*)out)[i] = o;
}

// ---- W [L][K][N] fp32  ->  Wt [L][N][K] bf16 (transpose via LDS tile) ----
__global__ void transpose_cvt(const float* __restrict__ W, unsigned short* __restrict__ Wt,
                              int Kdim, int Ndim) {
    __shared__ float tile[32][33];
    int l  = blockIdx.z;
    int k0 = blockIdx.x * 32;
    int n0 = blockIdx.y * 32;
    const float* Wl = W + (size_t)l * Kdim * Ndim;
    unsigned short* Wtl = Wt + (size_t)l * Kdim * Ndim;
    int c = threadIdx.x & 31, r = threadIdx.x >> 5;  // r: 0..7
#pragma unroll
    for (int i = 0; i < 4; i++)
        tile[r + i * 8][c] = Wl[(size_t)(k0 + r + i * 8) * Ndim + n0 + c];
    __syncthreads();
#pragma unroll
    for (int i = 0; i < 4; i++)
        Wtl[(size_t)(n0 + r + i * 8) * Kdim + k0 + c] = f2bf(tile[c][r + i * 8]);
}

// ---- embedding: x[row][d] = tok[idx[row]][d] + pos[row%SEQ][d]  (block=192, one row) ----
__global__ void embed_kernel(const int* __restrict__ idx, const float* __restrict__ tok,
                             const float* __restrict__ pos, float* __restrict__ x) {
    int row = blockIdx.x;
    int t = row & (SEQ - 1);
    int tr = idx[row];
    const float4* ts = (const float4*)(tok + (size_t)tr * DMODEL);
    const float4* ps = (const float4*)(pos + (size_t)t * DMODEL);
    float4* xs = (float4*)(x + (size_t)row * DMODEL);
    int i = threadIdx.x;  // 0..191
    float4 a = ts[i], b = ps[i];
    xs[i] = make_float4(a.x + b.x, a.y + b.y, a.z + b.z, a.w + b.w);
}

// ---- layernorm: x fp32 [rows][768] -> out bf16, block=256 per row ----
__global__ void layernorm_kernel(const float* __restrict__ x, const float* __restrict__ w,
                                 const float* __restrict__ b, unsigned short* __restrict__ out) {
    int row = blockIdx.x;
    const float* xr = x + (size_t)row * DMODEL;
    int t = threadIdx.x;
    float v0 = xr[t], v1 = xr[t + 256], v2 = xr[t + 512];
    float s = v0 + v1 + v2;
    float ss = v0 * v0 + v1 * v1 + v2 * v2;
#pragma unroll
    for (int off = 32; off >= 1; off >>= 1) {
        s  += __shfl_xor(s, off);
        ss += __shfl_xor(ss, off);
    }
    __shared__ float red[8];
    int wave = t >> 6, lane = t & 63;
    if (lane == 0) { red[wave] = s; red[wave + 4] = ss; }
    __syncthreads();
    s  = red[0] + red[1] + red[2] + red[3];
    ss = red[4] + red[5] + red[6] + red[7];
    float mu = s * (1.0f / DMODEL);
    float var = ss * (1.0f / DMODEL) - mu * mu;
    float rs = rsqrtf(var + 1e-5f);
    unsigned short* orow = out + (size_t)row * DMODEL;
    orow[t]       = f2bf((v0 - mu) * rs * w[t]       + b[t]);
    orow[t + 256] = f2bf((v1 - mu) * rs * w[t + 256] + b[t + 256]);
    orow[t + 512] = f2bf((v2 - mu) * rs * w[t + 512] + b[t + 512]);
}

// ---- GEMM: C[M,N] = epi(A[M,K] @ B'[N,K]^T + bias); 128x128 tile, 4 waves, mfma 16x16x32 bf16
//      NEW: double-buffered global_load_lds staging with counted vmcnt (never 0 in loop).
//      Raw s_barrier (NOT __syncthreads: that drains vmcnt(0) and kills the pipeline). ----
template <bool GELU_, bool RESID_, bool OUTBF16_, bool BIAS_>
__global__ __launch_bounds__(256) void gemm_kernel(
    const unsigned short* __restrict__ A,   // [M][K] bf16
    const unsigned short* __restrict__ Bw,  // [N][K] bf16
    const float* __restrict__ bias,         // [N]
    const float* resid,                     // [M][N] (may alias Cf)
    float* Cf, unsigned short* Cb,
    int Ndim, int Kdim) {
    const int bm = blockIdx.x * 128;
    const int bn = blockIdx.y * 128;
    __shared__ unsigned short As[2][128][32];   // linear dest for global_load_lds
    __shared__ unsigned short Bs[2][128][32];
    int tid = threadIdx.x;
    int wave = tid >> 6, lane = tid & 63;
    int wm = (wave >> 1) * 64, wn = (wave & 1) * 64;
    int quad = lane >> 4, ln = lane & 15;
    int srow = lane >> 2;            // 0..15
    int scol = (lane & 3) * 8;       // bf16 col within row
    f32x4 acc[4][4] = {};
    const int NT = Kdim >> 5;        // K-tiles of 32

#define GSTAGE(T, BUF)                                                                \
    _Pragma("unroll") for (int i_ = 0; i_ < 2; i_++) {                                \
        int ch_ = (wave << 1) | i_;                                                   \
        async_lds16(A  + (size_t)(bm + ch_ * 16 + srow) * Kdim + (T) * 32 + scol,     \
                    &As[BUF][ch_ * 16][0]);                                           \
        async_lds16(Bw + (size_t)(bn + ch_ * 16 + srow) * Kdim + (T) * 32 + scol,     \
                    &Bs[BUF][ch_ * 16][0]);                                           \
    }

    GSTAGE(0, 0)                               // 4 loads in flight (tile 0)
    for (int t = 0; t < NT; t++) {
        const int cur = t & 1;
        if (t + 1 < NT) {
            GSTAGE(t + 1, cur ^ 1)             // +4 loads (tile t+1): 8 outstanding
            asm volatile("s_waitcnt vmcnt(4)" ::: "memory");   // tile t retired; t+1 in flight
        } else {
            asm volatile("s_waitcnt vmcnt(0)" ::: "memory");   // last tile
        }
        __builtin_amdgcn_s_barrier(); asm volatile("" ::: "memory");
        bf16x8 af[4], bfr[4];
#pragma unroll
        for (int tm = 0; tm < 4; tm++) af[tm]  = *(const bf16x8*)(&As[cur][wm + tm * 16 + ln][quad * 8]);
#pragma unroll
        for (int tn = 0; tn < 4; tn++) bfr[tn] = *(const bf16x8*)(&Bs[cur][wn + tn * 16 + ln][quad * 8]);
#pragma unroll
        for (int tm = 0; tm < 4; tm++)
#pragma unroll
            for (int tn = 0; tn < 4; tn++)
                acc[tm][tn] = __builtin_amdgcn_mfma_f32_16x16x32_bf16(af[tm], bfr[tn], acc[tm][tn], 0, 0, 0);
        __builtin_amdgcn_s_barrier(); asm volatile("" ::: "memory");   // buf[cur] free for t+2 stage
    }
#undef GSTAGE

#pragma unroll
    for (int tm = 0; tm < 4; tm++)
#pragma unroll
        for (int tn = 0; tn < 4; tn++)
#pragma unroll
            for (int r = 0; r < 4; r++) {
                int row = bm + wm + tm * 16 + quad * 4 + r;
                int col = bn + wn + tn * 16 + ln;
                float c = acc[tm][tn][r];
                if (BIAS_) c += bias[col];
                if (GELU_) c = 0.5f * c * (1.0f + erff(c * 0.70710678118654752f));
                if (RESID_) c += resid[(size_t)row * Ndim + col];
                if (OUTBF16_) Cb[(size_t)row * Ndim + col] = f2bf(c);
                else          Cf[(size_t)row * Ndim + col] = c;
            }
}

// ============================================================================
// 256x256 8-phase GEMM (head only) — round-2 schedule + chunked XCD swizzle
// ============================================================================
__device__ __forceinline__ void stage_Ax(const unsigned short* A, int Kdim, int bm,
                                         unsigned short (*slotA)[64], int half, int ktile,
                                         int w, int lrow, int scol) {
#pragma unroll
    for (int j = 0; j < 2; j++) {
        int row = j * 128 + half * 64 + w * 8;   // wave-uniform base row
        const unsigned short* src = A + (size_t)(bm + row + lrow) * Kdim + ktile * 64 + scol;
        async_lds16(src, &slotA[row][0]);
    }
}
__device__ __forceinline__ void stage_Bx(const unsigned short* Bw, int Kdim, int bn,
                                         unsigned short (*slotB)[64], int half, int ktile,
                                         int w, int lrow, int scol) {
#pragma unroll
    for (int j = 0; j < 2; j++) {
        int gb = j * 64 + w * 8;
        int row = (gb >> 5) * 64 + half * 32 + (gb & 31);  // wave-uniform base row
        const unsigned short* src = Bw + (size_t)(bn + row + lrow) * Kdim + ktile * 64 + scol;
        async_lds16(src, &slotB[row][0]);
    }
}

#define PHASE(QM, QN, STAGE_STMT, VM_STMT)                                            \
  { bf16x8 af[4][2], bfv[2][2];                                                        \
    const char* Ab = (const char*)&lds[s][0][0][0];                                    \
    const char* Bb = (const char*)&lds[s][1][0][0];                                    \
    _Pragma("unroll") for (int j = 0; j < 4; j++) {                                    \
      int row = wr * 128 + (QM) * 64 + j * 16 + ln;                                    \
      int rs = row * 128, sw = (row & 7) << 4;                                         \
      _Pragma("unroll") for (int ks = 0; ks < 2; ks++)                                 \
        af[j][ks] = *(const bf16x8*)(Ab + rs + ((ks * 64 + quad * 16) ^ sw));          \
    }                                                                                  \
    _Pragma("unroll") for (int jn = 0; jn < 2; jn++) {                                 \
      int row = wc * 64 + (QN) * 32 + jn * 16 + ln;                                    \
      int rs = row * 128, sw = (row & 7) << 4;                                         \
      _Pragma("unroll") for (int ks = 0; ks < 2; ks++)                                 \
        bfv[jn][ks] = *(const bf16x8*)(Bb + rs + ((ks * 64 + quad * 16) ^ sw));        \
    }                                                                                  \
    STAGE_STMT;                                                                        \
    VM_STMT;                                                                           \
    __builtin_amdgcn_s_barrier(); asm volatile("" ::: "memory");                       \
    asm volatile("s_waitcnt lgkmcnt(0)" ::: "memory");                                 \
    __builtin_amdgcn_s_setprio(1);                                                     \
    _Pragma("unroll") for (int j = 0; j < 4; j++)                                      \
    _Pragma("unroll") for (int jn = 0; jn < 2; jn++)                                   \
    _Pragma("unroll") for (int ks = 0; ks < 2; ks++)                                   \
      acc[(QM) * 4 + j][(QN) * 2 + jn] = __builtin_amdgcn_mfma_f32_16x16x32_bf16(      \
          af[j][ks], bfv[jn][ks], acc[(QM) * 4 + j][(QN) * 2 + jn], 0, 0, 0);          \
    __builtin_amdgcn_s_setprio(0);                                                     \
    __builtin_amdgcn_s_barrier(); asm volatile("" ::: "memory"); }

__global__ __launch_bounds__(512, 2) void gemm256_kernel(
    const unsigned short* __restrict__ A,   // [M][K] bf16
    const unsigned short* __restrict__ Bw,  // [N][K] bf16
    float* __restrict__ Cf, int Ndim, int Kdim) {
    // chunked XCD swizzle (bijective: nwg = 16*125 = 2000, 2000 % 8 == 0).
    // HW dispatch round-robins linear id across 8 XCDs; remap so each XCD gets a
    // contiguous chunk of logical ids -> the 16 row-blocks sharing a B panel stay
    // on one XCD's L2.
    int lin = blockIdx.x + (int)gridDim.x * blockIdx.y;
    int nwg = (int)gridDim.x * (int)gridDim.y;
    int cpx = nwg >> 3;
    int swz = (lin & 7) * cpx + (lin >> 3);
    const int bm = (swz % (int)gridDim.x) * 256;
    const int bn = (swz / (int)gridDim.x) * 256;
    __shared__ unsigned short lds[2][2][256][64];   // [slot][A/B][row][col] = 128 KiB
    int tid = threadIdx.x;
    int w = tid >> 6, lane = tid & 63;
    int wr = w >> 2, wc = w & 3;
    int quad = lane >> 4, ln = lane & 15;
    int lrow = lane >> 3;                        // 0..7
    int scol = ((lane & 7) ^ lrow) << 3;         // pre-swizzled global col (bf16)
    f32x4 acc[8][4] = {};
    const int NT = Kdim >> 6;                    // 12 K-tiles of 64

    stage_Ax(A,  Kdim, bm, lds[0][0], 0, 0, w, lrow, scol);
    stage_Bx(Bw, Kdim, bn, lds[0][1], 0, 0, w, lrow, scol);
    stage_Ax(A,  Kdim, bm, lds[0][0], 1, 0, w, lrow, scol);
    stage_Bx(Bw, Kdim, bn, lds[0][1], 1, 0, w, lrow, scol);
    stage_Ax(A,  Kdim, bm, lds[1][0], 0, 1, w, lrow, scol);
    stage_Bx(Bw, Kdim, bn, lds[1][1], 0, 1, w, lrow, scol);
    asm volatile("s_waitcnt vmcnt(8)" ::: "memory");
    __builtin_amdgcn_s_barrier(); asm volatile("" ::: "memory");

    for (int t = 0; t < NT; t++) {
        const int s = t & 1;
        unsigned short (*nA)[64] = lds[s ^ 1][0];
        unsigned short (*nB)[64] = lds[s ^ 1][1];
        unsigned short (*cA)[64] = lds[s][0];
        unsigned short (*cB)[64] = lds[s][1];
        const bool st1 = (t + 1 < NT), st2 = (t + 2 < NT);

        PHASE(0, 0,
              if (st1) stage_Ax(A, Kdim, bm, nA, 1, t + 1, w, lrow, scol),
              if (st1) asm volatile("s_waitcnt vmcnt(6)" ::: "memory"))
        PHASE(0, 1,
              if (st1) stage_Bx(Bw, Kdim, bn, nB, 1, t + 1, w, lrow, scol),
              if (st1) asm volatile("s_waitcnt vmcnt(10)" ::: "memory"))
        PHASE(1, 0,
              if (st2) stage_Ax(A, Kdim, bm, cA, 0, t + 2, w, lrow, scol), )
        PHASE(1, 1,
              if (st2) stage_Bx(Bw, Kdim, bn, cB, 0, t + 2, w, lrow, scol),
              if (st2) { asm volatile("s_waitcnt vmcnt(8)" ::: "memory"); }
              else if (t == NT - 2) { asm volatile("s_waitcnt vmcnt(0)" ::: "memory"); })
    }

#pragma unroll
    for (int mf = 0; mf < 8; mf++)
#pragma unroll
        for (int nf = 0; nf < 4; nf++)
#pragma unroll
            for (int r = 0; r < 4; r++) {
                int row = bm + wr * 128 + mf * 16 + quad * 4 + r;
                int col = bn + wc * 64 + nf * 16 + ln;
                Cf[(size_t)row * Ndim + col] = acc[mf][nf][r];
            }
}

// ---- MFMA flash attention: unchanged from round 3 ----
__global__ __launch_bounds__(512, 2) void attn_kernel(const unsigned short* __restrict__ qkv,  // [4096][2304] bf16
                                                      unsigned short* __restrict__ out) {      // [4096][768] bf16
    int qtile = 15 - blockIdx.x;       // heavy tiles first (nkt = 2*qtile+2)
    int bh = blockIdx.y;               // 0..23
    int b = bh / NHEAD, h = bh % NHEAD;
    int q0 = qtile * 128;
    const unsigned short* base = qkv + (size_t)b * SEQ * (3 * DMODEL);

    __shared__ unsigned short Qs[128][72];
    __shared__ unsigned short Ks[64][72];
    __shared__ unsigned short Vs[64][72];   // transposed: Vs[d][key]
    __shared__ unsigned short Ps[128][72];

    int tid = threadIdx.x, wave = tid >> 6, lane = tid & 63;
    int quad = lane >> 4, ln = lane & 15;

    // stage Q (bf16), 512 threads x 2 chunks
    for (int c = tid; c < 1024; c += 512) {
        int r = c >> 3, col = (c & 7) * 8;
        *(bf16x8*)(&Qs[r][col]) =
            *(const bf16x8*)(base + (size_t)(q0 + r) * (3 * DMODEL) + h * HEADD + col);
    }
    __syncthreads();

    // wave owns q-rows [wave*16, wave*16+16)
    bf16x8 qf[2];
#pragma unroll
    for (int ks = 0; ks < 2; ks++)
        qf[ks] = *(const bf16x8*)(&Qs[wave * 16 + ln][ks * 32 + quad * 8]);

    f32x4 o[4] = {};
    float mst[4], lst[4];
#pragma unroll
    for (int i = 0; i < 4; i++) { mst[i] = -3.0e38f; lst[i] = 0.0f; }

    const float scale = 0.125f;  // 1/sqrt(64)
    int nkt = qtile * 2 + 2;

    for (int kt = 0; kt < nkt; kt++) {
        __syncthreads();
        // stage K [key][d] and V transposed [d][key]; one chunk per thread
        {
            int c = tid;  // 0..511
            int r = c >> 3, col = (c & 7) * 8;
            *(bf16x8*)(&Ks[r][col]) =
                *(const bf16x8*)(base + (size_t)(kt * 64 + r) * (3 * DMODEL) + DMODEL + h * HEADD + col);
            union { bf16x8 v; unsigned short u[8]; } vv;
            vv.v = *(const bf16x8*)(base + (size_t)(kt * 64 + r) * (3 * DMODEL) + 2 * DMODEL + h * HEADD + col);
#pragma unroll
            for (int j = 0; j < 8; j++) Vs[col + j][r] = vv.u[j];
        }
        __syncthreads();

        // S = Q K^T for this wave's 16 q-rows x 64 keys
        f32x4 s[4];
#pragma unroll
        for (int tn = 0; tn < 4; tn++) s[tn] = (f32x4){0.f, 0.f, 0.f, 0.f};
        bf16x8 kf[4][2];
#pragma unroll
        for (int tn = 0; tn < 4; tn++)
#pragma unroll
            for (int ks = 0; ks < 2; ks++)
                kf[tn][ks] = *(const bf16x8*)(&Ks[tn * 16 + ln][ks * 32 + quad * 8]);
#pragma unroll
        for (int tn = 0; tn < 4; tn++)
#pragma unroll
            for (int ks = 0; ks < 2; ks++)
                s[tn] = __builtin_amdgcn_mfma_f32_16x16x32_bf16(qf[ks], kf[tn][ks], s[tn], 0, 0, 0);

        // scale (+ causal mask only on diagonal-touching tiles)
        if (kt >= qtile * 2) {
#pragma unroll
            for (int tn = 0; tn < 4; tn++)
#pragma unroll
                for (int r = 0; r < 4; r++) {
                    int qi = q0 + wave * 16 + quad * 4 + r;
                    int kj = kt * 64 + tn * 16 + ln;
                    float sv = s[tn][r] * scale;
                    s[tn][r] = (kj > qi) ? -3.0e38f : sv;
                }
        } else {
#pragma unroll
            for (int tn = 0; tn < 4; tn++)
#pragma unroll
                for (int r = 0; r < 4; r++) s[tn][r] *= scale;
        }

        // online softmax per row r (rows replicated across the 16 ln-lanes of a quad-group)
#pragma unroll
        for (int r = 0; r < 4; r++) {
            float mx = fmaxf(fmaxf(s[0][r], s[1][r]), fmaxf(s[2][r], s[3][r]));
#pragma unroll
            for (int msk = 1; msk <= 8; msk <<= 1) mx = fmaxf(mx, __shfl_xor(mx, msk));
            float mnew = fmaxf(mst[r], mx);
            float alpha = __expf(mst[r] - mnew);
            mst[r] = mnew;
            float psum = 0.f;
#pragma unroll
            for (int tn = 0; tn < 4; tn++) {
                float p = __expf(s[tn][r] - mnew);
                s[tn][r] = p;
                psum += p;
            }
#pragma unroll
            for (int msk = 1; msk <= 8; msk <<= 1) psum += __shfl_xor(psum, msk);
            lst[r] = lst[r] * alpha + psum;
#pragma unroll
            for (int nd = 0; nd < 4; nd++) o[nd][r] *= alpha;
        }

        // P (C-layout) -> LDS (A-layout source); wave-private rows
#pragma unroll
        for (int tn = 0; tn < 4; tn++)
#pragma unroll
            for (int r = 0; r < 4; r++)
                Ps[wave * 16 + quad * 4 + r][tn * 16 + ln] = f2bf(s[tn][r]);

        // O += P V
        bf16x8 pf[2], vf[4][2];
#pragma unroll
        for (int ks = 0; ks < 2; ks++)
            pf[ks] = *(const bf16x8*)(&Ps[wave * 16 + ln][ks * 32 + quad * 8]);
#pragma unroll
        for (int nd = 0; nd < 4; nd++)
#pragma unroll
            for (int ks = 0; ks < 2; ks++)
                vf[nd][ks] = *(const bf16x8*)(&Vs[nd * 16 + ln][ks * 32 + quad * 8]);
#pragma unroll
        for (int nd = 0; nd < 4; nd++)
#pragma unroll
            for (int ks = 0; ks < 2; ks++)
                o[nd] = __builtin_amdgcn_mfma_f32_16x16x32_bf16(pf[ks], vf[nd][ks], o[nd], 0, 0, 0);
    }

    // normalize + store bf16 to [b*SEQ + t][h*64 + d]
#pragma unroll
    for (int r = 0; r < 4; r++) {
        float inv = 1.0f / lst[r];
        int trow = q0 + wave * 16 + quad * 4 + r;
#pragma unroll
        for (int nd = 0; nd < 4; nd++) {
            int col = h * HEADD + nd * 16 + ln;
            out[(size_t)(b * SEQ + trow) * DMODEL + col] = f2bf(o[nd][r] * inv);
        }
    }
}

extern "C" void kernel_launch(void* const* d_in, const int* in_sizes, int n_in,
                              void* d_out, int out_size, void* d_ws, size_t ws_size,
                              hipStream_t stream) {
    const int*   idx   = (const int*)  d_in[0];
    const float* tok   = (const float*)d_in[1];
    const float* pos   = (const float*)d_in[2];
    const float* ln1w  = (const float*)d_in[3];
    const float* ln1b  = (const float*)d_in[4];
    const float* Wqkv  = (const float*)d_in[5];
    const float* bqkv  = (const float*)d_in[6];
    const float* Wproj = (const float*)d_in[7];
    const float* bproj = (const float*)d_in[8];
    const float* ln2w  = (const float*)d_in[9];
    const float* ln2b  = (const float*)d_in[10];
    const float* Wfc   = (const float*)d_in[11];
    const float* bfc   = (const float*)d_in[12];
    const float* Wfc2  = (const float*)d_in[13];
    const float* bfc2  = (const float*)d_in[14];
    const float* lnfw  = (const float*)d_in[15];
    const float* lnfb  = (const float*)d_in[16];

    // scratch that dies before the head GEMM lives inside d_out (524 MB);
    // tokT + lnout survive into the head GEMM -> d_ws.
    char* ob = (char*)d_out;
    unsigned short* qkvb   = (unsigned short*)(ob + 0);          // 18,874,368 B (bf16)
    float*          x      = (float*)(ob + 18874368);            // 12,582,912 B
    unsigned short* ffact  = (unsigned short*)(ob + 31457280);   // 25,165,824 B
    unsigned short* attnb  = (unsigned short*)(ob + 56623104);   //  6,291,456 B
    unsigned short* WqkvT  = (unsigned short*)(ob + 62914560);   // 14,155,776 B
    unsigned short* WprojT = (unsigned short*)(ob + 77070336);   //  4,718,592 B
    unsigned short* WfcT   = (unsigned short*)(ob + 81788928);   // 18,874,368 B
    unsigned short* Wfc2T  = (unsigned short*)(ob + 100663296);  // 18,874,368 B (ends 119,537,664)
    unsigned short* tokT   = (unsigned short*)d_ws;                      // 49,152,000 B
    unsigned short* lnout  = (unsigned short*)((char*)d_ws + 49152000);  //  6,291,456 B

    // weight conversions
    cvt_bf16_x4<<<24000, 256, 0, stream>>>(tok, tokT, VOCAB * DMODEL / 4);
    transpose_cvt<<<dim3(24, 72, NLAYER), 256, 0, stream>>>(Wqkv,  WqkvT,  DMODEL, 3 * DMODEL);
    transpose_cvt<<<dim3(24, 24, NLAYER), 256, 0, stream>>>(Wproj, WprojT, DMODEL, DMODEL);
    transpose_cvt<<<dim3(24, 96, NLAYER), 256, 0, stream>>>(Wfc,   WfcT,   DMODEL, FFDIM);
    transpose_cvt<<<dim3(96, 24, NLAYER), 256, 0, stream>>>(Wfc2,  Wfc2T,  FFDIM,  DMODEL);

    embed_kernel<<<MROWS, 192, 0, stream>>>(idx, tok, pos, x);

    for (int l = 0; l < NLAYER; l++) {
        layernorm_kernel<<<MROWS, 256, 0, stream>>>(x, ln1w + l * DMODEL, ln1b + l * DMODEL, lnout);
        gemm_kernel<false, false, true, true><<<dim3(32, 18), 256, 0, stream>>>(
            lnout, WqkvT + (size_t)l * 3 * DMODEL * DMODEL, bqkv + l * 3 * DMODEL,
            nullptr, nullptr, qkvb, 3 * DMODEL, DMODEL);
        attn_kernel<<<dim3(16, BATCH * NHEAD), 512, 0, stream>>>(qkvb, attnb);
        gemm_kernel<false, true, false, true><<<dim3(32, 6), 256, 0, stream>>>(
            attnb, WprojT + (size_t)l * DMODEL * DMODEL, bproj + l * DMODEL,
            x, x, nullptr, DMODEL, DMODEL);
        layernorm_kernel<<<MROWS, 256, 0, stream>>>(x, ln2w + l * DMODEL, ln2b + l * DMODEL, lnout);
        gemm_kernel<true, false, true, true><<<dim3(32, 24), 256, 0, stream>>>(
            lnout, WfcT + (size_t)l * FFDIM * DMODEL, bfc + l * FFDIM,
            nullptr, nullptr, ffact, FFDIM, DMODEL);
        gemm_kernel<false, true, false, true><<<dim3(32, 6), 256, 0, stream>>>(
            ffact, Wfc2T + (size_t)l * FFDIM * DMODEL, bfc2 + l * DMODEL,
            x, x, nullptr, DMODEL, FFDIM);
    }

    layernorm_kernel<<<MROWS, 256, 0, stream>>>(x, lnfw, lnfb, lnout);
    // tied head: [4096,768] @ [32000,768]^T -> d_out fp32 (8-phase 256^2 + XCD swizzle)
    gemm256_kernel<<<dim3(16, 125), 512, 0, stream>>>(lnout, tokT, (float*)d_out, VOCAB, DMODEL);
}